// Round 3
// baseline (1698.109 us; speedup 1.0000x reference)
//
#include <hip/hip_runtime.h>
#include <hip/hip_bf16.h>

#define B_    2
#define SSRC  8192
#define TT    4096
#define NHN   16
#define NC    32
#define CS    256           // SSRC / NC
#define LOG100D 4.605170185988091368035982909368

typedef short s16x8 __attribute__((ext_vector_type(8)));
typedef float f32x4 __attribute__((ext_vector_type(4)));

typedef const __attribute__((address_space(1))) void* gas_ptr;
typedef __attribute__((address_space(3))) void* las_ptr;
#define GLDS16(g, l) __builtin_amdgcn_global_load_lds((gas_ptr)(g), (las_ptr)(l), 16, 0, 0)

__device__ __forceinline__ unsigned short f2bf(float f) {
    unsigned u = __float_as_uint(f);
    u = u + 0x7fffu + ((u >> 16) & 1u);
    return (unsigned short)(u >> 16);
}
__device__ __forceinline__ float bf2f(unsigned short h) {
    return __uint_as_float(((unsigned)h) << 16);
}
__device__ __forceinline__ double lrelu_d(double v) { return v >= 0.0 ? v : 0.2 * v; }
__device__ __forceinline__ double gelu_d(double u) {
    // jax.nn.gelu approximate=True: 0.5u(1+tanh(sqrt(2/pi)(u+0.044715u^3)))
    double a = 0.7978845608028654 * (u + 0.044715 * u * u * u);
    return 0.5 * u * (1.0 + tanh(a));
}
__device__ __forceinline__ double rsum16d(double v) {
    v += __shfl_xor(v, 1); v += __shfl_xor(v, 2);
    v += __shfl_xor(v, 4); v += __shfl_xor(v, 8);
    return v;
}
__device__ __forceinline__ double rmax16d(double v) {
    v = fmax(v, __shfl_xor(v, 1)); v = fmax(v, __shfl_xor(v, 2));
    v = fmax(v, __shfl_xor(v, 4)); v = fmax(v, __shfl_xor(v, 8));
    return v;
}
__device__ __forceinline__ double rsum64d(double v) {
    v += __shfl_xor(v, 1); v += __shfl_xor(v, 2); v += __shfl_xor(v, 4);
    v += __shfl_xor(v, 8); v += __shfl_xor(v, 16); v += __shfl_xor(v, 32);
    return v;
}

// ---------------- top-k phase A: per-chunk top-16 (exact f32, stable) ----------------
__global__ __launch_bounds__(256) void topk_partial(
    const float* __restrict__ c1, const float* __restrict__ c2,
    float* __restrict__ cd, int* __restrict__ ci)
{
    int t = blockIdx.x * 256 + threadIdx.x;
    int ch = blockIdx.y, b = blockIdx.z;
    const float* p1 = c1 + ((size_t)b * SSRC + (size_t)ch * CS) * TT + t;
    const float* p2 = c2 + ((size_t)b * SSRC + (size_t)ch * CS) * TT + t;
    float dv[16]; int iv[16];
#pragma unroll
    for (int j = 0; j < 16; j++) { dv[j] = INFINITY; iv[j] = 0x7fffffff; }
    float dmax = INFINITY; int imax = 0x7fffffff, mslot = 0;
    int sbase = ch * CS;
    for (int s = 0; s < CS; s += 4) {
        float a0 = p1[(size_t)(s + 0) * TT], a1 = p1[(size_t)(s + 1) * TT];
        float a2 = p1[(size_t)(s + 2) * TT], a3 = p1[(size_t)(s + 3) * TT];
        float b0 = p2[(size_t)(s + 0) * TT], b1 = p2[(size_t)(s + 1) * TT];
        float b2 = p2[(size_t)(s + 2) * TT], b3 = p2[(size_t)(s + 3) * TT];
        // exact IEEE mul/add to match numpy f32 (no fma contraction)
        float d0 = __fadd_rn(__fmul_rn(a0, a0), __fmul_rn(b0, b0));
        float d1 = __fadd_rn(__fmul_rn(a1, a1), __fmul_rn(b1, b1));
        float d2 = __fadd_rn(__fmul_rn(a2, a2), __fmul_rn(b2, b2));
        float d3 = __fadd_rn(__fmul_rn(a3, a3), __fmul_rn(b3, b3));
#pragma unroll
        for (int u = 0; u < 4; u++) {
            float dd = (u == 0) ? d0 : (u == 1) ? d1 : (u == 2) ? d2 : d3;
            if (dd < dmax) {   // strict <: stable vs scan order
                int si = sbase + s + u;
#pragma unroll
                for (int j = 0; j < 16; j++) if (j == mslot) { dv[j] = dd; iv[j] = si; }
                dmax = -INFINITY; imax = -1;
#pragma unroll
                for (int j = 0; j < 16; j++) {
                    bool g = (dv[j] > dmax) || (dv[j] == dmax && iv[j] > imax);
                    dmax = g ? dv[j] : dmax; imax = g ? iv[j] : imax; mslot = g ? j : mslot;
                }
            }
        }
    }
    size_t base = ((size_t)(b * NC + ch) * 16) * TT + t;
#pragma unroll
    for (int j = 0; j < 16; j++) { cd[base + (size_t)j * TT] = dv[j]; ci[base + (size_t)j * TT] = iv[j]; }
}

// ---------------- top-k phase B: merge chunks, sort, emit indices ----------------
__global__ __launch_bounds__(64) void topk_merge(
    const float* __restrict__ cd, const int* __restrict__ ci, int* __restrict__ knn)
{
    int t = blockIdx.x * 64 + threadIdx.x;
    int b = blockIdx.y;
    float dv[16]; int iv[16];
#pragma unroll
    for (int j = 0; j < 16; j++) { dv[j] = INFINITY; iv[j] = 0x7fffffff; }
    float dmax = INFINITY; int imax = 0x7fffffff; int mslot = 0;
    for (int c = 0; c < NC * 16; c++) {
        float dd = cd[((size_t)(b * NC * 16 + c)) * TT + t];
        int   ii = ci[((size_t)(b * NC * 16 + c)) * TT + t];
        bool ins = (dd < dmax) || (dd == dmax && ii < imax);
        if (ins) {
#pragma unroll
            for (int j = 0; j < 16; j++) if (j == mslot) { dv[j] = dd; iv[j] = ii; }
            dmax = -INFINITY; imax = -1;
#pragma unroll
            for (int j = 0; j < 16; j++) {
                bool g = (dv[j] > dmax) || (dv[j] == dmax && iv[j] > imax);
                dmax = g ? dv[j] : dmax; imax = g ? iv[j] : imax; mslot = g ? j : mslot;
            }
        }
    }
    // rank-sort lexicographic (d, idx) ascending, static indexing
#pragma unroll
    for (int i = 0; i < 16; i++) {
        int rank = 0;
#pragma unroll
        for (int j = 0; j < 16; j++) {
            bool less = (dv[j] < dv[i]) || (dv[j] == dv[i] && iv[j] < iv[i]);
            rank += less ? 1 : 0;
        }
        knn[((size_t)b * TT + t) * 16 + rank] = iv[i];
    }
}

// ------- weight transpose + split-bf16 convert (mu_W1/mu_W2 -> W^T hi/lo) -------
__global__ __launch_bounds__(256) void wconv(
    const float* __restrict__ Wa, const float* __restrict__ Wb,
    unsigned short* __restrict__ Oah, unsigned short* __restrict__ Oal,
    unsigned short* __restrict__ Obh, unsigned short* __restrict__ Obl)
{
    const float* W = blockIdx.z ? Wb : Wa;
    unsigned short* Oh = blockIdx.z ? Obh : Oah;
    unsigned short* Ol = blockIdx.z ? Obl : Oal;
    __shared__ float tile[64][65];
    int tx = threadIdx.x & 63, ty = threadIdx.x >> 6;
    int n0 = blockIdx.x * 64, k0 = blockIdx.y * 64;
#pragma unroll
    for (int r = ty; r < 64; r += 4) tile[r][tx] = W[(size_t)(k0 + r) * 1024 + n0 + tx];
    __syncthreads();
#pragma unroll
    for (int r = ty; r < 64; r += 4) {
        float v = tile[tx][r];
        unsigned short hi = f2bf(v);
        Oh[(size_t)(n0 + r) * 1024 + k0 + tx] = hi;
        Ol[(size_t)(n0 + r) * 1024 + k0 + tx] = f2bf(v - bf2f(hi));
    }
}

// ---------------- per-token network, f64 arithmetic (LDS stays f32) ----------------
__global__ __launch_bounds__(256, 1) void token_net(
    const float* __restrict__ x, const float* __restrict__ c1, const float* __restrict__ c2,
    const int* __restrict__ knn,
    const float* __restrict__ peW1, const float* __restrict__ peb1,
    const float* __restrict__ peW2, const float* __restrict__ peb2,
    const float* __restrict__ Wq, const float* __restrict__ Wk,
    const float* __restrict__ Wv, const float* __restrict__ lsc,
    const float* __restrict__ Wo, const float* __restrict__ bo,
    const float* __restrict__ g1, const float* __restrict__ be1,
    const float* __restrict__ g2, const float* __restrict__ be2,
    const float* __restrict__ g3, const float* __restrict__ be3,
    const float* __restrict__ mW1, const float* __restrict__ mb1,
    const float* __restrict__ mW2, const float* __restrict__ mb2,
    unsigned short* __restrict__ hnh, unsigned short* __restrict__ hnl)
{
    __shared__ float s_peW1[256], s_peb1[128], s_peW2[8192], s_peb2[64];
    __shared__ float s_Wq[4096], s_Wk[4096], s_WoV[256], s_bo[64];
    __shared__ float s_mW1[8192], s_mb1[128], s_mW2[128];
    __shared__ float s_g1[64], s_be1[64], s_g2[64], s_be2[64], s_g3[1024], s_be3[1024];
    __shared__ float s_scr[4][2352];   // per-wave: big[2304] + c1g[16]+c2g[16]+x[16]

    int tid = threadIdx.x, lane = tid & 63, w = tid >> 6;

    // ---- stage weights (f32 — exact input data) ----
    if (tid < 256) s_peW1[tid] = peW1[tid];
    if (tid < 128) { s_peb1[tid] = peb1[tid]; s_mb1[tid] = mb1[tid]; s_mW2[tid] = mW2[tid]; }
    if (tid < 64) {
        s_peb2[tid] = peb2[tid]; s_bo[tid] = bo[tid];
        s_g1[tid] = g1[tid]; s_be1[tid] = be1[tid]; s_g2[tid] = g2[tid]; s_be2[tid] = be2[tid];
        // WoV[head][e] = sum_hd Wv[head*16+hd] * Wo[(head*16+hd)*64 + e]  (rank-1 v collapse), f64
        for (int hh = 0; hh < 4; hh++) {
            double a = 0.0;
            for (int hd = 0; hd < 16; hd++)
                a += (double)Wv[hh * 16 + hd] * (double)Wo[(hh * 16 + hd) * 64 + tid];
            s_WoV[hh * 64 + tid] = (float)a;
        }
    }
    for (int i = tid; i < 8192; i += 256) { s_peW2[i] = peW2[i]; s_mW1[i] = mW1[i]; }
    for (int i = tid; i < 4096; i += 256) { s_Wq[i] = Wq[i]; s_Wk[i] = Wk[i]; }
    for (int i = tid; i < 1024; i += 256) { s_g3[i] = g3[i]; s_be3[i] = be3[i]; }
    __syncthreads();

    int head = lane >> 4, mm = lane & 15;
    double scaleh = exp(fmin((double)lsc[head], LOG100D));
    double mb2s = (double)mb2[0];
    double wov0 = (double)s_WoV[lane], wov1 = (double)s_WoV[64 + lane];
    double wov2 = (double)s_WoV[128 + lane], wov3 = (double)s_WoV[192 + lane];
    float* big = s_scr[w];
    float* sc1 = big + 2304; float* sc2 = big + 2320; float* sx = big + 2336;

    for (int it = 0; it < 8; ++it) {
        int tk = blockIdx.x * 32 + w * 8 + it;
        int bb = tk >> 12, tt = tk & (TT - 1);
        __syncthreads();
        if (lane < 16) {
            int s = knn[(size_t)tk * 16 + lane];
            sc1[lane] = c1[((size_t)bb * SSRC + s) * TT + tt];
            sc2[lane] = c2[((size_t)bb * SSRC + s) * TT + tt];
            sx[lane]  = x[bb * SSRC + s];
        }
        __syncthreads();

        // ---- PE layer 1 (f64): g[n][f] = gelu(c1g*W1[0,f]+c2g*W1[1,f]+b1[f]); gT stride 18
        {
            double w0a = s_peW1[lane], w1a = s_peW1[128 + lane], ba = s_peb1[lane];
            double w0b = s_peW1[64 + lane], w1b = s_peW1[192 + lane], bbv = s_peb1[64 + lane];
#pragma unroll
            for (int n = 0; n < 16; n++) {
                double a_ = (double)sc1[n], b_ = (double)sc2[n];
                big[lane * 18 + n]        = (float)gelu_d(a_ * w0a + b_ * w1a + ba);
                big[(lane + 64) * 18 + n] = (float)gelu_d(a_ * w0b + b_ * w1b + bbv);
            }
        }
        __syncthreads();

        // ---- PE layer 2 + x + LN1 (f64) -> h
        double h[16];
        {
            double acc[16];
#pragma unroll
            for (int n = 0; n < 16; n++) acc[n] = (double)s_peb2[lane];
            for (int f = 0; f < 128; f++) {
                double wv = (double)s_peW2[f * 64 + lane];
#pragma unroll
                for (int n = 0; n < 16; n += 2) {
                    float2 gv = *(const float2*)&big[f * 18 + n];
                    acc[n]     += (double)gv.x * wv;
                    acc[n + 1] += (double)gv.y * wv;
                }
            }
            double gv = (double)s_g1[lane], bv = (double)s_be1[lane];
#pragma unroll
            for (int n = 0; n < 16; n++) {
                double v = acc[n] + (double)sx[n];
                double m = rsum64d(v) * (1.0 / 64.0);
                double d = v - m;
                double var = rsum64d(d * d) * (1.0 / 64.0);
                h[n] = d / sqrt(var + 1e-5) * gv + bv;
            }
        }
        __syncthreads();
        // write hT[k=lane][n] (f32)
#pragma unroll
        for (int n = 0; n < 16; n++) big[lane * 18 + n] = (float)h[n];
        __syncthreads();

        // ---- q = h@Wq, k = h@Wk (f64 accum from f32 LDS)
        double q[16], k2[16];
#pragma unroll
        for (int n = 0; n < 16; n++) { q[n] = 0.0; k2[n] = 0.0; }
        for (int kk = 0; kk < 64; kk++) {
            double wq = (double)s_Wq[kk * 64 + lane], wk = (double)s_Wk[kk * 64 + lane];
#pragma unroll
            for (int n = 0; n < 16; n += 2) {
                float2 hv = *(const float2*)&big[kk * 18 + n];
                q[n]  += (double)hv.x * wq; q[n + 1]  += (double)hv.y * wq;
                k2[n] += (double)hv.x * wk; k2[n + 1] += (double)hv.y * wk;
            }
        }
        // cosine-normalize per (row, head), f64
#pragma unroll
        for (int n = 0; n < 16; n++) {
            double sq = rsum16d(q[n] * q[n]);   q[n]  /= sqrt(sq + 1e-12);
            double sk = rsum16d(k2[n] * k2[n]); k2[n] /= sqrt(sk + 1e-12);
        }
        __syncthreads();
        // write qnT (big[0..]) and knT (big[1152..]) f32
#pragma unroll
        for (int n = 0; n < 16; n++) {
            big[lane * 18 + n]        = (float)q[n];
            big[1152 + lane * 18 + n] = (float)k2[n];
        }
        __syncthreads();

        // ---- S = qn@kn^T * scale, softmax over m, A[n] = sum_m att*x[m]  (f64)
        double A_[16];
        {
            double S[16];
#pragma unroll
            for (int n = 0; n < 16; n++) S[n] = 0.0;
            for (int hd = 0; hd < 16; hd++) {
                int r = head * 16 + hd;
                double kf = (double)big[1152 + r * 18 + mm];
#pragma unroll
                for (int n = 0; n < 16; n += 2) {
                    float2 qq = *(const float2*)&big[r * 18 + n];
                    S[n] += (double)qq.x * kf; S[n + 1] += (double)qq.y * kf;
                }
            }
            double xv = (double)sx[mm];
#pragma unroll
            for (int n = 0; n < 16; n++) {
                double sv = S[n] * scaleh;
                double mx = rmax16d(sv);
                double e = exp(sv - mx);
                double se = rsum16d(e);
                double att = e / se;
                A_[n] = rsum16d(att * xv);
            }
        }
        // ---- (o@Wo+bo) via WoV + residual + LN2 (f64)
        {
            double gv = (double)s_g2[lane], bv = (double)s_be2[lane], bov = (double)s_bo[lane];
#pragma unroll
            for (int n = 0; n < 16; n++) {
                double a0 = __shfl(A_[n], mm), a1 = __shfl(A_[n], 16 + mm);
                double a2 = __shfl(A_[n], 32 + mm), a3 = __shfl(A_[n], 48 + mm);
                double v = h[n] + a0 * wov0 + a1 * wov1 + a2 * wov2 + a3 * wov3 + bov;
                double m = rsum64d(v) * (1.0 / 64.0);
                double d = v - m;
                double var = rsum64d(d * d) * (1.0 / 64.0);
                h[n] = d / sqrt(var + 1e-5) * gv + bv;
            }
        }
        __syncthreads();
#pragma unroll
        for (int n = 0; n < 16; n++) big[lane * 18 + n] = (float)h[n];
        __syncthreads();

        // ---- mnh: h += lrelu(lrelu(h@mW1+b1)@mW2+b2)  (f64)
        {
            double t1a[16], t1b[16];
#pragma unroll
            for (int n = 0; n < 16; n++) { t1a[n] = (double)s_mb1[lane]; t1b[n] = (double)s_mb1[64 + lane]; }
            for (int kk = 0; kk < 64; kk++) {
                double wa = (double)s_mW1[kk * 128 + lane], wb = (double)s_mW1[kk * 128 + 64 + lane];
#pragma unroll
                for (int n = 0; n < 16; n += 2) {
                    float2 hv = *(const float2*)&big[kk * 18 + n];
                    t1a[n] += (double)hv.x * wa; t1a[n + 1] += (double)hv.y * wa;
                    t1b[n] += (double)hv.x * wb; t1b[n + 1] += (double)hv.y * wb;
                }
            }
            double w2a = (double)s_mW2[lane], w2b = (double)s_mW2[64 + lane];
#pragma unroll
            for (int n = 0; n < 16; n++) {
                double p = lrelu_d(t1a[n]) * w2a + lrelu_d(t1b[n]) * w2b;
                p = rsum64d(p);
                h[n] += lrelu_d(p + mb2s);
            }
        }
        // ---- LN3 over flattened 1024 (f64) + split-bf16 store
        {
            double s1 = 0.0;
#pragma unroll
            for (int n = 0; n < 16; n++) s1 += h[n];
            s1 = rsum64d(s1) * (1.0 / 1024.0);
            double s2v = 0.0;
#pragma unroll
            for (int n = 0; n < 16; n++) { double d = h[n] - s1; s2v += d * d; }
            s2v = rsum64d(s2v) * (1.0 / 1024.0);
            double rs = 1.0 / sqrt(s2v + 1e-5);
            unsigned short* oph = hnh + (size_t)tk * 1024 + lane;
            unsigned short* opl = hnl + (size_t)tk * 1024 + lane;
#pragma unroll
            for (int n = 0; n < 16; n++) {
                double v = (h[n] - s1) * rs * (double)s_g3[n * 64 + lane] + (double)s_be3[n * 64 + lane];
                unsigned short hi = f2bf((float)v);
                oph[n * 64] = hi;
                opl[n * 64] = f2bf((float)(v - (double)bf2f(hi)));
            }
        }
    }
}

// ------- split-bf16 MFMA GEMM: out = lrelu(A@B + bias), A=Ah+Al, B=Bh+Bl -------
// A [M,K] row-major (hi/lo); BT [N,K] row-major (pre-transposed weights, hi/lo)
#define AH_OFF 0
#define AL_OFF 4096
#define BH_OFF 8192
#define BL_OFF 12288
template<int OUTSPLIT>
__global__ __launch_bounds__(256) void gemm_split(
    const unsigned short* __restrict__ Ah, const unsigned short* __restrict__ Al,
    const unsigned short* __restrict__ Bh, const unsigned short* __restrict__ Bl,
    const float* __restrict__ bias,
    unsigned short* __restrict__ oh, unsigned short* __restrict__ ol,
    float* __restrict__ of, int M, int N, int K)
{
    __shared__ unsigned short SM[16384];   // single array: explicit region offsets
    int tid = threadIdx.x, lane = tid & 63, w = tid >> 6;
    int wm = w >> 1, wn = w & 1;
    int m0 = blockIdx.y * 128, n0 = blockIdx.x * 128;
    f32x4 acc[4][4];
#pragma unroll
    for (int i = 0; i < 4; i++)
#pragma unroll
        for (int j = 0; j < 4; j++) acc[i][j] = (f32x4){0.f, 0.f, 0.f, 0.f};
    int row = tid >> 2, c8 = (tid & 3) * 8;
    size_t aoff = (size_t)(m0 + row) * K + c8;
    size_t boff = (size_t)(n0 + row) * K + c8;
    for (int kk = 0; kk < K; kk += 32) {
        __syncthreads();
        GLDS16(Ah + aoff + kk,                   SM + AH_OFF + tid * 8);
        GLDS16(Ah + aoff + (size_t)64 * K + kk,  SM + AH_OFF + 2048 + tid * 8);
        GLDS16(Al + aoff + kk,                   SM + AL_OFF + tid * 8);
        GLDS16(Al + aoff + (size_t)64 * K + kk,  SM + AL_OFF + 2048 + tid * 8);
        GLDS16(Bh + boff + kk,                   SM + BH_OFF + tid * 8);
        GLDS16(Bh + boff + (size_t)64 * K + kk,  SM + BH_OFF + 2048 + tid * 8);
        GLDS16(Bl + boff + kk,                   SM + BL_OFF + tid * 8);
        GLDS16(Bl + boff + (size_t)64 * K + kk,  SM + BL_OFF + 2048 + tid * 8);
        asm volatile("s_waitcnt vmcnt(0)" ::: "memory");
        __syncthreads();
        int kh = (lane >> 4) * 8, rA = wm * 64 + (lane & 15), rB = wn * 64 + (lane & 15);
        s16x8 afh[4], afl[4], bfh[4], bfl[4];
#pragma unroll
        for (int i = 0; i < 4; i++) {
            afh[i] = *(const s16x8*)&SM[AH_OFF + (rA + i * 16) * 32 + kh];
            afl[i] = *(const s16x8*)&SM[AL_OFF + (rA + i * 16) * 32 + kh];
            bfh[i] = *(const s16x8*)&SM[BH_OFF + (rB + i * 16) * 32 + kh];
            bfl[i] = *(const s16x8*)&SM[BL_OFF + (rB + i * 16) * 32 + kh];
        }
#pragma unroll
        for (int i = 0; i < 4; i++)
#pragma unroll
            for (int j = 0; j < 4; j++) {
                acc[i][j] = __builtin_amdgcn_mfma_f32_16x16x32_bf16(afl[i], bfh[j], acc[i][j], 0, 0, 0);
                acc[i][j] = __builtin_amdgcn_mfma_f32_16x16x32_bf16(afh[i], bfl[j], acc[i][j], 0, 0, 0);
                acc[i][j] = __builtin_amdgcn_mfma_f32_16x16x32_bf16(afh[i], bfh[j], acc[i][j], 0, 0, 0);
            }
    }
    float bc[4];
#pragma unroll
    for (int j = 0; j < 4; j++) bc[j] = bias[n0 + wn * 64 + j * 16 + (lane & 15)];
#pragma unroll
    for (int i = 0; i < 4; i++) {
#pragma unroll
        for (int j = 0; j < 4; j++) {
#pragma unroll
            for (int r = 0; r < 4; r++) {
                int rw = m0 + wm * 64 + i * 16 + (lane >> 4) * 4 + r;
                int cl = n0 + wn * 64 + j * 16 + (lane & 15);
                float v = acc[i][j][r] + bc[j];
                v = v >= 0.f ? v : 0.2f * v;
                if (OUTSPLIT) {
                    unsigned short hi = f2bf(v);
                    oh[(size_t)rw * N + cl] = hi;
                    ol[(size_t)rw * N + cl] = f2bf(v - bf2f(hi));
                } else {
                    of[(size_t)rw * N + cl] = v;
                }
            }
        }
    }
}

extern "C" void kernel_launch(void* const* d_in, const int* in_sizes, int n_in,
                              void* d_out, int out_size, void* d_ws, size_t ws_size,
                              hipStream_t stream)
{
    const float* x    = (const float*)d_in[0];
    const float* c1   = (const float*)d_in[1];
    const float* c2   = (const float*)d_in[2];
    const float* peW1 = (const float*)d_in[3];
    const float* peb1 = (const float*)d_in[4];
    const float* peW2 = (const float*)d_in[5];
    const float* peb2 = (const float*)d_in[6];
    const float* Wq   = (const float*)d_in[7];
    const float* Wk   = (const float*)d_in[8];
    const float* Wv   = (const float*)d_in[9];
    const float* lsc  = (const float*)d_in[10];
    const float* Wo   = (const float*)d_in[11];
    const float* bo   = (const float*)d_in[12];
    const float* g1   = (const float*)d_in[13];
    const float* be1  = (const float*)d_in[14];
    const float* g2   = (const float*)d_in[15];
    const float* be2  = (const float*)d_in[16];
    const float* g3   = (const float*)d_in[17];
    const float* be3  = (const float*)d_in[18];
    const float* mW1  = (const float*)d_in[19];
    const float* mb1  = (const float*)d_in[20];
    const float* mW2  = (const float*)d_in[21];
    const float* mb2  = (const float*)d_in[22];
    const float* muW1 = (const float*)d_in[23];
    const float* mub1 = (const float*)d_in[24];
    const float* muW2 = (const float*)d_in[25];
    const float* mub2 = (const float*)d_in[26];

    const size_t MB = (size_t)1 << 20;
    char* ws = (char*)d_ws;
    // [0,16M): cand_d, later y1h   [16M,32M): cand_i, later y1l
    float*          cand_d = (float*)(ws);
    int*            cand_i = (int*)(ws + 16 * MB);
    unsigned short* y1h    = (unsigned short*)(ws);
    unsigned short* y1l    = (unsigned short*)(ws + 16 * MB);
    int*            knn    = (int*)(ws + 32 * MB);
    unsigned short* w1th   = (unsigned short*)(ws + 33 * MB);
    unsigned short* w1tl   = (unsigned short*)(ws + 35 * MB);
    unsigned short* w2th   = (unsigned short*)(ws + 37 * MB);
    unsigned short* w2tl   = (unsigned short*)(ws + 39 * MB);
    unsigned short* hnh    = (unsigned short*)(ws + 41 * MB);
    unsigned short* hnl    = (unsigned short*)(ws + 57 * MB);
    (void)in_sizes; (void)n_in; (void)out_size; (void)ws_size;

    wconv<<<dim3(16, 16, 2), 256, 0, stream>>>(muW1, muW2, w1th, w1tl, w2th, w2tl);
    topk_partial<<<dim3(TT / 256, NC, B_), 256, 0, stream>>>(c1, c2, cand_d, cand_i);
    topk_merge<<<dim3(TT / 64, B_), 64, 0, stream>>>(cand_d, cand_i, knn);
    token_net<<<dim3(256), 256, 0, stream>>>(x, c1, c2, knn, peW1, peb1, peW2, peb2,
                                             Wq, Wk, Wv, lsc, Wo, bo, g1, be1, g2, be2,
                                             g3, be3, mW1, mb1, mW2, mb2, hnh, hnl);
    gemm_split<1><<<dim3(8, 64), 256, 0, stream>>>(hnh, hnl, w1th, w1tl, mub1,
                                                   y1h, y1l, (float*)nullptr, 8192, 1024, 1024);
    gemm_split<0><<<dim3(8, 64), 256, 0, stream>>>(y1h, y1l, w2th, w2tl, mub2,
                                                   (unsigned short*)nullptr, (unsigned short*)nullptr,
                                                   (float*)d_out, 8192, 1024, 1024);
}

// Round 4
// 1233.550 us; speedup vs baseline: 1.3766x; 1.3766x over previous
//
#include <hip/hip_runtime.h>
#include <hip/hip_bf16.h>

#define B_    2
#define SSRC  8192
#define TT    4096
#define NHN   16
#define NC    32
#define CS    256           // SSRC / NC
#define LOG100D 4.605170185988091368035982909368

typedef short s16x8 __attribute__((ext_vector_type(8)));
typedef float f32x4 __attribute__((ext_vector_type(4)));

typedef const __attribute__((address_space(1))) void* gas_ptr;
typedef __attribute__((address_space(3))) void* las_ptr;
#define GLDS16(g, l) __builtin_amdgcn_global_load_lds((gas_ptr)(g), (las_ptr)(l), 16, 0, 0)

// wave-local LDS fence: scratch is per-wave, no cross-wave barrier needed
#define WFENCE asm volatile("s_waitcnt lgkmcnt(0)" ::: "memory")

__device__ __forceinline__ unsigned short f2bf(float f) {
    unsigned u = __float_as_uint(f);
    u = u + 0x7fffu + ((u >> 16) & 1u);
    return (unsigned short)(u >> 16);
}
__device__ __forceinline__ float bf2f(unsigned short h) {
    return __uint_as_float(((unsigned)h) << 16);
}
__device__ __forceinline__ double lrelu_d(double v) { return v >= 0.0 ? v : 0.2 * v; }
__device__ __forceinline__ double gelu_d(double u) {
    double a = 0.7978845608028654 * (u + 0.044715 * u * u * u);
    return 0.5 * u * (1.0 + tanh(a));
}
__device__ __forceinline__ double rsum16d(double v) {
    v += __shfl_xor(v, 1); v += __shfl_xor(v, 2);
    v += __shfl_xor(v, 4); v += __shfl_xor(v, 8);
    return v;
}
__device__ __forceinline__ double rmax16d(double v) {
    v = fmax(v, __shfl_xor(v, 1)); v = fmax(v, __shfl_xor(v, 2));
    v = fmax(v, __shfl_xor(v, 4)); v = fmax(v, __shfl_xor(v, 8));
    return v;
}
__device__ __forceinline__ double rsum64d(double v) {
    v += __shfl_xor(v, 1); v += __shfl_xor(v, 2); v += __shfl_xor(v, 4);
    v += __shfl_xor(v, 8); v += __shfl_xor(v, 16); v += __shfl_xor(v, 32);
    return v;
}

// ---------------- top-k phase A: per-chunk top-16 (exact f32, stable) ----------------
__global__ __launch_bounds__(256) void topk_partial(
    const float* __restrict__ c1, const float* __restrict__ c2,
    float* __restrict__ cd, int* __restrict__ ci)
{
    int t = blockIdx.x * 256 + threadIdx.x;
    int ch = blockIdx.y, b = blockIdx.z;
    const float* p1 = c1 + ((size_t)b * SSRC + (size_t)ch * CS) * TT + t;
    const float* p2 = c2 + ((size_t)b * SSRC + (size_t)ch * CS) * TT + t;
    float dv[16]; int iv[16];
#pragma unroll
    for (int j = 0; j < 16; j++) { dv[j] = INFINITY; iv[j] = 0x7fffffff; }
    float dmax = INFINITY; int imax = 0x7fffffff, mslot = 0;
    int sbase = ch * CS;
    for (int s = 0; s < CS; s += 4) {
        float a0 = p1[(size_t)(s + 0) * TT], a1 = p1[(size_t)(s + 1) * TT];
        float a2 = p1[(size_t)(s + 2) * TT], a3 = p1[(size_t)(s + 3) * TT];
        float b0 = p2[(size_t)(s + 0) * TT], b1 = p2[(size_t)(s + 1) * TT];
        float b2 = p2[(size_t)(s + 2) * TT], b3 = p2[(size_t)(s + 3) * TT];
        float d0 = __fadd_rn(__fmul_rn(a0, a0), __fmul_rn(b0, b0));
        float d1 = __fadd_rn(__fmul_rn(a1, a1), __fmul_rn(b1, b1));
        float d2 = __fadd_rn(__fmul_rn(a2, a2), __fmul_rn(b2, b2));
        float d3 = __fadd_rn(__fmul_rn(a3, a3), __fmul_rn(b3, b3));
#pragma unroll
        for (int u = 0; u < 4; u++) {
            float dd = (u == 0) ? d0 : (u == 1) ? d1 : (u == 2) ? d2 : d3;
            if (dd < dmax) {
                int si = sbase + s + u;
#pragma unroll
                for (int j = 0; j < 16; j++) if (j == mslot) { dv[j] = dd; iv[j] = si; }
                dmax = -INFINITY; imax = -1;
#pragma unroll
                for (int j = 0; j < 16; j++) {
                    bool g = (dv[j] > dmax) || (dv[j] == dmax && iv[j] > imax);
                    dmax = g ? dv[j] : dmax; imax = g ? iv[j] : imax; mslot = g ? j : mslot;
                }
            }
        }
    }
    size_t base = ((size_t)(b * NC + ch) * 16) * TT + t;
#pragma unroll
    for (int j = 0; j < 16; j++) { cd[base + (size_t)j * TT] = dv[j]; ci[base + (size_t)j * TT] = iv[j]; }
}

// ---------------- top-k merge level 1: 32 chunk-lists -> 4 group-lists ----------------
__global__ __launch_bounds__(64) void topk_merge1(
    const float* __restrict__ cd, const int* __restrict__ ci,
    float* __restrict__ c2d, int* __restrict__ c2i)
{
    int t = blockIdx.x * 64 + threadIdx.x;
    int g = blockIdx.y, b = blockIdx.z;
    float dv[16]; int iv[16];
#pragma unroll
    for (int j = 0; j < 16; j++) { dv[j] = INFINITY; iv[j] = 0x7fffffff; }
    float dmax = INFINITY; int imax = 0x7fffffff; int mslot = 0;
    for (int c = g * 128; c < (g + 1) * 128; c++) {
        float dd = cd[((size_t)(b * NC * 16 + c)) * TT + t];
        int   ii = ci[((size_t)(b * NC * 16 + c)) * TT + t];
        bool ins = (dd < dmax) || (dd == dmax && ii < imax);
        if (ins) {
#pragma unroll
            for (int j = 0; j < 16; j++) if (j == mslot) { dv[j] = dd; iv[j] = ii; }
            dmax = -INFINITY; imax = -1;
#pragma unroll
            for (int j = 0; j < 16; j++) {
                bool gg = (dv[j] > dmax) || (dv[j] == dmax && iv[j] > imax);
                dmax = gg ? dv[j] : dmax; imax = gg ? iv[j] : imax; mslot = gg ? j : mslot;
            }
        }
    }
    size_t base = ((size_t)((b * 4 + g) * 16)) * TT + t;
#pragma unroll
    for (int j = 0; j < 16; j++) { c2d[base + (size_t)j * TT] = dv[j]; c2i[base + (size_t)j * TT] = iv[j]; }
}

// ---------------- top-k merge level 2: 4 lists -> sorted knn ----------------
__global__ __launch_bounds__(64) void topk_merge2(
    const float* __restrict__ c2d, const int* __restrict__ c2i, int* __restrict__ knn)
{
    int t = blockIdx.x * 64 + threadIdx.x;
    int b = blockIdx.y;
    float dv[16]; int iv[16];
#pragma unroll
    for (int j = 0; j < 16; j++) { dv[j] = INFINITY; iv[j] = 0x7fffffff; }
    float dmax = INFINITY; int imax = 0x7fffffff; int mslot = 0;
    for (int c = 0; c < 64; c++) {
        float dd = c2d[((size_t)(b * 64 + c)) * TT + t];
        int   ii = c2i[((size_t)(b * 64 + c)) * TT + t];
        bool ins = (dd < dmax) || (dd == dmax && ii < imax);
        if (ins) {
#pragma unroll
            for (int j = 0; j < 16; j++) if (j == mslot) { dv[j] = dd; iv[j] = ii; }
            dmax = -INFINITY; imax = -1;
#pragma unroll
            for (int j = 0; j < 16; j++) {
                bool gg = (dv[j] > dmax) || (dv[j] == dmax && iv[j] > imax);
                dmax = gg ? dv[j] : dmax; imax = gg ? iv[j] : imax; mslot = gg ? j : mslot;
            }
        }
    }
#pragma unroll
    for (int i = 0; i < 16; i++) {
        int rank = 0;
#pragma unroll
        for (int j = 0; j < 16; j++) {
            bool less = (dv[j] < dv[i]) || (dv[j] == dv[i] && iv[j] < iv[i]);
            rank += less ? 1 : 0;
        }
        knn[((size_t)b * TT + t) * 16 + rank] = iv[i];
    }
}

// ------- weight transpose + split-bf16 convert (mu_W1/mu_W2 -> W^T hi/lo) -------
__global__ __launch_bounds__(256) void wconv(
    const float* __restrict__ Wa, const float* __restrict__ Wb,
    unsigned short* __restrict__ Oah, unsigned short* __restrict__ Oal,
    unsigned short* __restrict__ Obh, unsigned short* __restrict__ Obl)
{
    const float* W = blockIdx.z ? Wb : Wa;
    unsigned short* Oh = blockIdx.z ? Obh : Oah;
    unsigned short* Ol = blockIdx.z ? Obl : Oal;
    __shared__ float tile[64][65];
    int tx = threadIdx.x & 63, ty = threadIdx.x >> 6;
    int n0 = blockIdx.x * 64, k0 = blockIdx.y * 64;
#pragma unroll
    for (int r = ty; r < 64; r += 4) tile[r][tx] = W[(size_t)(k0 + r) * 1024 + n0 + tx];
    __syncthreads();
#pragma unroll
    for (int r = ty; r < 64; r += 4) {
        float v = tile[tx][r];
        unsigned short hi = f2bf(v);
        Oh[(size_t)(n0 + r) * 1024 + k0 + tx] = hi;
        Ol[(size_t)(n0 + r) * 1024 + k0 + tx] = f2bf(v - bf2f(hi));
    }
}

// ============ stage A: gather + PE MLP + LN1 -> h (f32 global) ============
__global__ __launch_bounds__(256) void tok_pe(
    const float* __restrict__ x, const float* __restrict__ c1, const float* __restrict__ c2,
    const int* __restrict__ knn,
    const float* __restrict__ peW1, const float* __restrict__ peb1,
    const float* __restrict__ peW2, const float* __restrict__ peb2,
    const float* __restrict__ g1, const float* __restrict__ be1,
    float* __restrict__ hout)
{
    __shared__ float s_peW1[256], s_peb1[128], s_peW2[8192], s_peb2[64], s_g1[64], s_be1[64];
    __shared__ float s_scr[4][2352];
    int tid = threadIdx.x, lane = tid & 63, w = tid >> 6;
    if (tid < 256) s_peW1[tid] = peW1[tid];
    if (tid < 128) s_peb1[tid] = peb1[tid];
    if (tid < 64) { s_peb2[tid] = peb2[tid]; s_g1[tid] = g1[tid]; s_be1[tid] = be1[tid]; }
    for (int i = tid; i < 8192; i += 256) s_peW2[i] = peW2[i];
    __syncthreads();

    float* big = s_scr[w];
    float* sc1 = big + 2304; float* sc2 = big + 2320; float* sx = big + 2336;
    double w0a = s_peW1[lane], w1a = s_peW1[128 + lane], ba = s_peb1[lane];
    double w0b = s_peW1[64 + lane], w1b = s_peW1[192 + lane], bbv = s_peb1[64 + lane];
    double gv = (double)s_g1[lane], bv = (double)s_be1[lane];
    double pb2 = (double)s_peb2[lane];

    for (int it = 0; it < 4; ++it) {
        int tk = blockIdx.x * 16 + w * 4 + it;
        int bb = tk >> 12, tt = tk & (TT - 1);
        if (lane < 16) {
            int s = knn[(size_t)tk * 16 + lane];
            sc1[lane] = c1[((size_t)bb * SSRC + s) * TT + tt];
            sc2[lane] = c2[((size_t)bb * SSRC + s) * TT + tt];
            sx[lane]  = x[bb * SSRC + s];
        }
        WFENCE;
        // PE layer 1 (f64), gT stored f32 rows stride 18
#pragma unroll
        for (int n = 0; n < 16; n++) {
            double a_ = (double)sc1[n], b_ = (double)sc2[n];
            big[lane * 18 + n]        = (float)gelu_d(a_ * w0a + b_ * w1a + ba);
            big[(lane + 64) * 18 + n] = (float)gelu_d(a_ * w0b + b_ * w1b + bbv);
        }
        WFENCE;
        // PE layer 2 + x + LN1 (f64)
        double acc[16];
#pragma unroll
        for (int n = 0; n < 16; n++) acc[n] = pb2;
        for (int f = 0; f < 128; f++) {
            double wv = (double)s_peW2[f * 64 + lane];
#pragma unroll
            for (int n = 0; n < 16; n += 2) {
                float2 gvv = *(const float2*)&big[f * 18 + n];
                acc[n]     += (double)gvv.x * wv;
                acc[n + 1] += (double)gvv.y * wv;
            }
        }
        float* op = hout + (size_t)tk * 1024 + lane;
#pragma unroll
        for (int n = 0; n < 16; n++) {
            double v = acc[n] + (double)sx[n];
            double m = rsum64d(v) * (1.0 / 64.0);
            double d = v - m;
            double var = rsum64d(d * d) * (1.0 / 64.0);
            op[n * 64] = (float)(d / sqrt(var + 1e-5) * gv + bv);
        }
    }
}

// ============ stage B: q/k + cosine attn + WoV residual + LN2 (h in-place) ============
__global__ __launch_bounds__(256) void tok_attn(
    const float* __restrict__ x, const int* __restrict__ knn,
    const float* __restrict__ Wq, const float* __restrict__ Wk,
    const float* __restrict__ Wv, const float* __restrict__ lsc,
    const float* __restrict__ Wo, const float* __restrict__ bo,
    const float* __restrict__ g2, const float* __restrict__ be2,
    float* __restrict__ hio)
{
    __shared__ float s_Wq[4096], s_Wk[4096], s_WoV[256], s_bo[64], s_g2[64], s_be2[64];
    __shared__ float s_scr[4][2320];
    int tid = threadIdx.x, lane = tid & 63, w = tid >> 6;
    if (tid < 64) {
        s_bo[tid] = bo[tid]; s_g2[tid] = g2[tid]; s_be2[tid] = be2[tid];
        for (int hh = 0; hh < 4; hh++) {
            double a = 0.0;
            for (int hd = 0; hd < 16; hd++)
                a += (double)Wv[hh * 16 + hd] * (double)Wo[(hh * 16 + hd) * 64 + tid];
            s_WoV[hh * 64 + tid] = (float)a;
        }
    }
    for (int i = tid; i < 4096; i += 256) { s_Wq[i] = Wq[i]; s_Wk[i] = Wk[i]; }
    __syncthreads();

    int head = lane >> 4, mm = lane & 15;
    double scaleh = exp(fmin((double)lsc[head], LOG100D));
    double wov0 = (double)s_WoV[lane], wov1 = (double)s_WoV[64 + lane];
    double wov2 = (double)s_WoV[128 + lane], wov3 = (double)s_WoV[192 + lane];
    double gv = (double)s_g2[lane], bv = (double)s_be2[lane], bov = (double)s_bo[lane];
    float* big = s_scr[w];
    float* sx = big + 2304;

    for (int it = 0; it < 4; ++it) {
        int tk = blockIdx.x * 16 + w * 4 + it;
        int bb = tk >> 12;
        if (lane < 16) {
            int s = knn[(size_t)tk * 16 + lane];
            sx[lane] = x[bb * SSRC + s];
        }
        float* hp = hio + (size_t)tk * 1024 + lane;
        double h[16];
#pragma unroll
        for (int n = 0; n < 16; n++) {
            h[n] = (double)hp[n * 64];
            big[lane * 18 + n] = (float)h[n];   // hT[k=lane][n]
        }
        WFENCE;
        // q = h@Wq, k = h@Wk (f64)
        double q[16], k2[16];
#pragma unroll
        for (int n = 0; n < 16; n++) { q[n] = 0.0; k2[n] = 0.0; }
        for (int kk = 0; kk < 64; kk++) {
            double wq = (double)s_Wq[kk * 64 + lane], wk = (double)s_Wk[kk * 64 + lane];
#pragma unroll
            for (int n = 0; n < 16; n += 2) {
                float2 hv = *(const float2*)&big[kk * 18 + n];
                q[n]  += (double)hv.x * wq; q[n + 1]  += (double)hv.y * wq;
                k2[n] += (double)hv.x * wk; k2[n + 1] += (double)hv.y * wk;
            }
        }
#pragma unroll
        for (int n = 0; n < 16; n++) {
            double sq = rsum16d(q[n] * q[n]);   q[n]  /= sqrt(sq + 1e-12);
            double sk = rsum16d(k2[n] * k2[n]); k2[n] /= sqrt(sk + 1e-12);
        }
        WFENCE;   // ensure hT reads retired before overwrite
#pragma unroll
        for (int n = 0; n < 16; n++) {
            big[lane * 18 + n]        = (float)q[n];
            big[1152 + lane * 18 + n] = (float)k2[n];
        }
        WFENCE;
        // S = qn@kn^T * scale, softmax, A = att @ x
        double A_[16];
        {
            double S[16];
#pragma unroll
            for (int n = 0; n < 16; n++) S[n] = 0.0;
            for (int hd = 0; hd < 16; hd++) {
                int r = head * 16 + hd;
                double kf = (double)big[1152 + r * 18 + mm];
#pragma unroll
                for (int n = 0; n < 16; n += 2) {
                    float2 qq = *(const float2*)&big[r * 18 + n];
                    S[n] += (double)qq.x * kf; S[n + 1] += (double)qq.y * kf;
                }
            }
            double xv = (double)sx[mm];
#pragma unroll
            for (int n = 0; n < 16; n++) {
                double sv = S[n] * scaleh;
                double mx = rmax16d(sv);
                double e = exp(sv - mx);
                double se = rsum16d(e);
                A_[n] = rsum16d((e / se) * xv);
            }
        }
        // WoV residual + LN2, write back
#pragma unroll
        for (int n = 0; n < 16; n++) {
            double a0 = __shfl(A_[n], mm), a1 = __shfl(A_[n], 16 + mm);
            double a2 = __shfl(A_[n], 32 + mm), a3 = __shfl(A_[n], 48 + mm);
            double v = h[n] + a0 * wov0 + a1 * wov1 + a2 * wov2 + a3 * wov3 + bov;
            double m = rsum64d(v) * (1.0 / 64.0);
            double d = v - m;
            double var = rsum64d(d * d) * (1.0 / 64.0);
            hp[n * 64] = (float)(d / sqrt(var + 1e-5) * gv + bv);
        }
    }
}

// ============ stage C: mnh MLP + LN3 -> hn split-bf16 ============
__global__ __launch_bounds__(256) void tok_mnh(
    const float* __restrict__ hin,
    const float* __restrict__ mW1, const float* __restrict__ mb1,
    const float* __restrict__ mW2, const float* __restrict__ mb2,
    const float* __restrict__ g3, const float* __restrict__ be3,
    unsigned short* __restrict__ hnh, unsigned short* __restrict__ hnl)
{
    __shared__ float s_mW1[8192], s_mb1[128], s_mW2[128], s_g3[1024], s_be3[1024];
    __shared__ float s_scr[4][1152];
    int tid = threadIdx.x, lane = tid & 63, w = tid >> 6;
    if (tid < 128) { s_mb1[tid] = mb1[tid]; s_mW2[tid] = mW2[tid]; }
    for (int i = tid; i < 8192; i += 256) s_mW1[i] = mW1[i];
    for (int i = tid; i < 1024; i += 256) { s_g3[i] = g3[i]; s_be3[i] = be3[i]; }
    __syncthreads();

    double mb2s = (double)mb2[0];
    double mb1a = (double)s_mb1[lane], mb1b = (double)s_mb1[64 + lane];
    double w2a = (double)s_mW2[lane], w2b = (double)s_mW2[64 + lane];
    float* big = s_scr[w];

    for (int it = 0; it < 4; ++it) {
        int tk = blockIdx.x * 16 + w * 4 + it;
        const float* hp = hin + (size_t)tk * 1024 + lane;
        double h[16];
#pragma unroll
        for (int n = 0; n < 16; n++) {
            h[n] = (double)hp[n * 64];
            big[lane * 18 + n] = (float)h[n];
        }
        WFENCE;
        double t1a[16], t1b[16];
#pragma unroll
        for (int n = 0; n < 16; n++) { t1a[n] = mb1a; t1b[n] = mb1b; }
        for (int kk = 0; kk < 64; kk++) {
            double wa = (double)s_mW1[kk * 128 + lane], wb = (double)s_mW1[kk * 128 + 64 + lane];
#pragma unroll
            for (int n = 0; n < 16; n += 2) {
                float2 hv = *(const float2*)&big[kk * 18 + n];
                t1a[n] += (double)hv.x * wa; t1a[n + 1] += (double)hv.y * wa;
                t1b[n] += (double)hv.x * wb; t1b[n + 1] += (double)hv.y * wb;
            }
        }
#pragma unroll
        for (int n = 0; n < 16; n++) {
            double p = lrelu_d(t1a[n]) * w2a + lrelu_d(t1b[n]) * w2b;
            p = rsum64d(p);
            h[n] += lrelu_d(p + mb2s);
        }
        // LN3 over flattened 1024 + split-bf16 store
        double s1 = 0.0;
#pragma unroll
        for (int n = 0; n < 16; n++) s1 += h[n];
        s1 = rsum64d(s1) * (1.0 / 1024.0);
        double s2v = 0.0;
#pragma unroll
        for (int n = 0; n < 16; n++) { double d = h[n] - s1; s2v += d * d; }
        s2v = rsum64d(s2v) * (1.0 / 1024.0);
        double rs = 1.0 / sqrt(s2v + 1e-5);
        unsigned short* oph = hnh + (size_t)tk * 1024 + lane;
        unsigned short* opl = hnl + (size_t)tk * 1024 + lane;
#pragma unroll
        for (int n = 0; n < 16; n++) {
            double v = (h[n] - s1) * rs * (double)s_g3[n * 64 + lane] + (double)s_be3[n * 64 + lane];
            unsigned short hi = f2bf((float)v);
            oph[n * 64] = hi;
            opl[n * 64] = f2bf((float)(v - (double)bf2f(hi)));
        }
    }
}

// ------- split-bf16 MFMA GEMM: out = lrelu(A@B + bias), A=Ah+Al, B=Bh+Bl -------
#define AH_OFF 0
#define AL_OFF 4096
#define BH_OFF 8192
#define BL_OFF 12288
template<int OUTSPLIT>
__global__ __launch_bounds__(256) void gemm_split(
    const unsigned short* __restrict__ Ah, const unsigned short* __restrict__ Al,
    const unsigned short* __restrict__ Bh, const unsigned short* __restrict__ Bl,
    const float* __restrict__ bias,
    unsigned short* __restrict__ oh, unsigned short* __restrict__ ol,
    float* __restrict__ of, int M, int N, int K)
{
    __shared__ unsigned short SM[16384];
    int tid = threadIdx.x, lane = tid & 63, w = tid >> 6;
    int wm = w >> 1, wn = w & 1;
    int m0 = blockIdx.y * 128, n0 = blockIdx.x * 128;
    f32x4 acc[4][4];
#pragma unroll
    for (int i = 0; i < 4; i++)
#pragma unroll
        for (int j = 0; j < 4; j++) acc[i][j] = (f32x4){0.f, 0.f, 0.f, 0.f};
    int row = tid >> 2, c8 = (tid & 3) * 8;
    size_t aoff = (size_t)(m0 + row) * K + c8;
    size_t boff = (size_t)(n0 + row) * K + c8;
    for (int kk = 0; kk < K; kk += 32) {
        __syncthreads();
        GLDS16(Ah + aoff + kk,                   SM + AH_OFF + tid * 8);
        GLDS16(Ah + aoff + (size_t)64 * K + kk,  SM + AH_OFF + 2048 + tid * 8);
        GLDS16(Al + aoff + kk,                   SM + AL_OFF + tid * 8);
        GLDS16(Al + aoff + (size_t)64 * K + kk,  SM + AL_OFF + 2048 + tid * 8);
        GLDS16(Bh + boff + kk,                   SM + BH_OFF + tid * 8);
        GLDS16(Bh + boff + (size_t)64 * K + kk,  SM + BH_OFF + 2048 + tid * 8);
        GLDS16(Bl + boff + kk,                   SM + BL_OFF + tid * 8);
        GLDS16(Bl + boff + (size_t)64 * K + kk,  SM + BL_OFF + 2048 + tid * 8);
        asm volatile("s_waitcnt vmcnt(0)" ::: "memory");
        __syncthreads();
        int kh = (lane >> 4) * 8, rA = wm * 64 + (lane & 15), rB = wn * 64 + (lane & 15);
        s16x8 afh[4], afl[4], bfh[4], bfl[4];
#pragma unroll
        for (int i = 0; i < 4; i++) {
            afh[i] = *(const s16x8*)&SM[AH_OFF + (rA + i * 16) * 32 + kh];
            afl[i] = *(const s16x8*)&SM[AL_OFF + (rA + i * 16) * 32 + kh];
            bfh[i] = *(const s16x8*)&SM[BH_OFF + (rB + i * 16) * 32 + kh];
            bfl[i] = *(const s16x8*)&SM[BL_OFF + (rB + i * 16) * 32 + kh];
        }
#pragma unroll
        for (int i = 0; i < 4; i++)
#pragma unroll
            for (int j = 0; j < 4; j++) {
                acc[i][j] = __builtin_amdgcn_mfma_f32_16x16x32_bf16(afl[i], bfh[j], acc[i][j], 0, 0, 0);
                acc[i][j] = __builtin_amdgcn_mfma_f32_16x16x32_bf16(afh[i], bfl[j], acc[i][j], 0, 0, 0);
                acc[i][j] = __builtin_amdgcn_mfma_f32_16x16x32_bf16(afh[i], bfh[j], acc[i][j], 0, 0, 0);
            }
    }
    float bc[4];
#pragma unroll
    for (int j = 0; j < 4; j++) bc[j] = bias[n0 + wn * 64 + j * 16 + (lane & 15)];
#pragma unroll
    for (int i = 0; i < 4; i++) {
#pragma unroll
        for (int j = 0; j < 4; j++) {
#pragma unroll
            for (int r = 0; r < 4; r++) {
                int rw = m0 + wm * 64 + i * 16 + (lane >> 4) * 4 + r;
                int cl = n0 + wn * 64 + j * 16 + (lane & 15);
                float v = acc[i][j][r] + bc[j];
                v = v >= 0.f ? v : 0.2f * v;
                if (OUTSPLIT) {
                    unsigned short hi = f2bf(v);
                    oh[(size_t)rw * N + cl] = hi;
                    ol[(size_t)rw * N + cl] = f2bf(v - bf2f(hi));
                } else {
                    of[(size_t)rw * N + cl] = v;
                }
            }
        }
    }
}

extern "C" void kernel_launch(void* const* d_in, const int* in_sizes, int n_in,
                              void* d_out, int out_size, void* d_ws, size_t ws_size,
                              hipStream_t stream)
{
    const float* x    = (const float*)d_in[0];
    const float* c1   = (const float*)d_in[1];
    const float* c2   = (const float*)d_in[2];
    const float* peW1 = (const float*)d_in[3];
    const float* peb1 = (const float*)d_in[4];
    const float* peW2 = (const float*)d_in[5];
    const float* peb2 = (const float*)d_in[6];
    const float* Wq   = (const float*)d_in[7];
    const float* Wk   = (const float*)d_in[8];
    const float* Wv   = (const float*)d_in[9];
    const float* lsc  = (const float*)d_in[10];
    const float* Wo   = (const float*)d_in[11];
    const float* bo   = (const float*)d_in[12];
    const float* g1   = (const float*)d_in[13];
    const float* be1  = (const float*)d_in[14];
    const float* g2   = (const float*)d_in[15];
    const float* be2  = (const float*)d_in[16];
    const float* g3   = (const float*)d_in[17];
    const float* be3  = (const float*)d_in[18];
    const float* mW1  = (const float*)d_in[19];
    const float* mb1  = (const float*)d_in[20];
    const float* mW2  = (const float*)d_in[21];
    const float* mb2  = (const float*)d_in[22];
    const float* muW1 = (const float*)d_in[23];
    const float* mub1 = (const float*)d_in[24];
    const float* muW2 = (const float*)d_in[25];
    const float* mub2 = (const float*)d_in[26];

    const size_t MB = (size_t)1 << 20;
    char* ws = (char*)d_ws;
    // timeline-safe layout (see analysis): total ~80.5 MB
    float*          cand_d = (float*)(ws);                    // 0-16, dead after merge1
    int*            cand_i = (int*)(ws + 16 * MB);            // 16-32, dead after merge1
    float*          c2d    = (float*)(ws + 34 * MB);          // 34-36, dead after merge2
    int*            c2i    = (int*)(ws + 36 * MB);            // 36-38, dead after merge2
    float*          hbuf   = (float*)(ws + 38 * MB);          // 38-72, dead after tok_mnh
    unsigned short* hnh    = (unsigned short*)(ws);           // 0-16.8 (cand dead)
    unsigned short* hnl    = (unsigned short*)(ws + 17 * MB); // 17-33.8 (cand/knn-safe)
    unsigned short* y1h    = (unsigned short*)(ws + 38 * MB); // 38-55 (h dead)
    unsigned short* y1l    = (unsigned short*)(ws + 55 * MB); // 55-72
    unsigned short* w1th   = (unsigned short*)(ws + 72 * MB);
    unsigned short* w1tl   = (unsigned short*)(ws + 74 * MB);
    unsigned short* w2th   = (unsigned short*)(ws + 76 * MB);
    unsigned short* w2tl   = (unsigned short*)(ws + 78 * MB);
    int*            knn    = (int*)(ws + 80 * MB);            // 80-80.5
    (void)in_sizes; (void)n_in; (void)out_size; (void)ws_size;

    wconv<<<dim3(16, 16, 2), 256, 0, stream>>>(muW1, muW2, w1th, w1tl, w2th, w2tl);
    topk_partial<<<dim3(TT / 256, NC, B_), 256, 0, stream>>>(c1, c2, cand_d, cand_i);
    topk_merge1<<<dim3(TT / 64, 4, B_), 64, 0, stream>>>(cand_d, cand_i, c2d, c2i);
    topk_merge2<<<dim3(TT / 64, B_), 64, 0, stream>>>(c2d, c2i, knn);
    tok_pe<<<dim3(512), 256, 0, stream>>>(x, c1, c2, knn, peW1, peb1, peW2, peb2, g1, be1, hbuf);
    tok_attn<<<dim3(512), 256, 0, stream>>>(x, knn, Wq, Wk, Wv, lsc, Wo, bo, g2, be2, hbuf);
    tok_mnh<<<dim3(512), 256, 0, stream>>>(hbuf, mW1, mb1, mW2, mb2, g3, be3, hnh, hnl);
    gemm_split<1><<<dim3(8, 64), 256, 0, stream>>>(hnh, hnl, w1th, w1tl, mub1,
                                                   y1h, y1l, (float*)nullptr, 8192, 1024, 1024);
    gemm_split<0><<<dim3(8, 64), 256, 0, stream>>>(y1h, y1l, w2th, w2tl, mub2,
                                                   (unsigned short*)nullptr, (unsigned short*)nullptr,
                                                   (float*)d_out, 8192, 1024, 1024);
}

// Round 5
// 893.447 us; speedup vs baseline: 1.9006x; 1.3807x over previous
//
#include <hip/hip_runtime.h>
#include <hip/hip_bf16.h>

#define B_    2
#define SSRC  8192
#define TT    4096
#define NHN   16
#define NC    64
#define CS    128           // SSRC / NC
#define LOG100D 4.605170185988091368035982909368

typedef short s16x8 __attribute__((ext_vector_type(8)));
typedef float f32x4 __attribute__((ext_vector_type(4)));
typedef unsigned long long u64;

typedef const __attribute__((address_space(1))) void* gas_ptr;
typedef __attribute__((address_space(3))) void* las_ptr;
#define GLDS16(g, l) __builtin_amdgcn_global_load_lds((gas_ptr)(g), (las_ptr)(l), 16, 0, 0)

// wave-local LDS fence: scratch is per-wave, no cross-wave barrier needed
#define WFENCE asm volatile("s_waitcnt lgkmcnt(0)" ::: "memory")

__device__ __forceinline__ unsigned short f2bf(float f) {
    unsigned u = __float_as_uint(f);
    u = u + 0x7fffu + ((u >> 16) & 1u);
    return (unsigned short)(u >> 16);
}
__device__ __forceinline__ float bf2f(unsigned short h) {
    return __uint_as_float(((unsigned)h) << 16);
}
__device__ __forceinline__ double lrelu_d(double v) { return v >= 0.0 ? v : 0.2 * v; }
__device__ __forceinline__ double gelu_d(double u) {
    double a = 0.7978845608028654 * (u + 0.044715 * u * u * u);
    return 0.5 * u * (1.0 + tanh(a));
}
__device__ __forceinline__ double rsum16d(double v) {
    v += __shfl_xor(v, 1); v += __shfl_xor(v, 2);
    v += __shfl_xor(v, 4); v += __shfl_xor(v, 8);
    return v;
}
__device__ __forceinline__ double rmax16d(double v) {
    v = fmax(v, __shfl_xor(v, 1)); v = fmax(v, __shfl_xor(v, 2));
    v = fmax(v, __shfl_xor(v, 4)); v = fmax(v, __shfl_xor(v, 8));
    return v;
}
__device__ __forceinline__ double rsum64d(double v) {
    v += __shfl_xor(v, 1); v += __shfl_xor(v, 2); v += __shfl_xor(v, 4);
    v += __shfl_xor(v, 8); v += __shfl_xor(v, 16); v += __shfl_xor(v, 32);
    return v;
}

// sorted-ascending u64-key insert: k[0..15], k[15] = current worst.
// key = (float_bits(d) << 32) | src_index  -- exact (d asc, idx asc) lex order.
__device__ __forceinline__ void kinsert(u64 (&k)[16], u64 nk) {
    bool sj = nk < k[15];
#pragma unroll
    for (int j = 15; j >= 1; j--) {
        bool sjm = nk < k[j - 1];
        k[j] = sjm ? k[j - 1] : (sj ? nk : k[j]);
        sj = sjm;
    }
    k[0] = sj ? nk : k[0];
}

// ---------------- top-k phase A: per-chunk sorted top-16 (u64 keys) ----------------
__global__ __launch_bounds__(256) void topk_partial(
    const float* __restrict__ c1, const float* __restrict__ c2,
    u64* __restrict__ cand)
{
    int t = blockIdx.x * 256 + threadIdx.x;
    int ch = blockIdx.y, b = blockIdx.z;
    const float* p1 = c1 + ((size_t)b * SSRC + (size_t)ch * CS) * TT + t;
    const float* p2 = c2 + ((size_t)b * SSRC + (size_t)ch * CS) * TT + t;
    u64 k[16];
#pragma unroll
    for (int j = 0; j < 16; j++) k[j] = ~0ull;
    int sbase = ch * CS;
    for (int s = 0; s < CS; s += 4) {
        float a0 = p1[(size_t)(s + 0) * TT], a1 = p1[(size_t)(s + 1) * TT];
        float a2 = p1[(size_t)(s + 2) * TT], a3 = p1[(size_t)(s + 3) * TT];
        float b0 = p2[(size_t)(s + 0) * TT], b1 = p2[(size_t)(s + 1) * TT];
        float b2 = p2[(size_t)(s + 2) * TT], b3 = p2[(size_t)(s + 3) * TT];
        // exact IEEE mul/add to match numpy f32 (no fma contraction)
        float d0 = __fadd_rn(__fmul_rn(a0, a0), __fmul_rn(b0, b0));
        float d1 = __fadd_rn(__fmul_rn(a1, a1), __fmul_rn(b1, b1));
        float d2 = __fadd_rn(__fmul_rn(a2, a2), __fmul_rn(b2, b2));
        float d3 = __fadd_rn(__fmul_rn(a3, a3), __fmul_rn(b3, b3));
#pragma unroll
        for (int u = 0; u < 4; u++) {
            float dd = (u == 0) ? d0 : (u == 1) ? d1 : (u == 2) ? d2 : d3;
            u64 nk = ((u64)__float_as_uint(dd) << 32) | (unsigned)(sbase + s + u);
            if (nk < k[15]) kinsert(k, nk);
        }
    }
    u64* dst = cand + ((size_t)(b * NC + ch) * 16) * TT + t;
#pragma unroll
    for (int j = 0; j < 16; j++) dst[(size_t)j * TT] = k[j];
}

// ---------------- top-k merge level 1: 64 chunk-lists -> 8 group-lists ----------------
__global__ __launch_bounds__(64) void topk_merge1(
    const u64* __restrict__ cand, u64* __restrict__ c2c)
{
    int t = blockIdx.x * 64 + threadIdx.x;
    int g = blockIdx.y, b = blockIdx.z;
    u64 k[16];
#pragma unroll
    for (int j = 0; j < 16; j++) k[j] = ~0ull;
    for (int c = g * 8; c < g * 8 + 8; c++) {
        const u64* src = cand + ((size_t)(b * NC + c) * 16) * TT + t;
        for (int j = 0; j < 16; j++) {
            u64 nk = src[(size_t)j * TT];
            bool ins = nk < k[15];
            if (!__any(ins)) break;   // chunk sorted asc & k[15] monotone dec -> rest can't insert
            if (ins) kinsert(k, nk);
        }
    }
    u64* dst = c2c + ((size_t)((b * 8 + g) * 16)) * TT + t;
#pragma unroll
    for (int j = 0; j < 16; j++) dst[(size_t)j * TT] = k[j];
}

// ---------------- top-k merge level 2: 8 lists -> sorted knn indices ----------------
__global__ __launch_bounds__(64) void topk_merge2(
    const u64* __restrict__ c2c, int* __restrict__ knn)
{
    int t = blockIdx.x * 64 + threadIdx.x;
    int b = blockIdx.y;
    u64 k[16];
#pragma unroll
    for (int j = 0; j < 16; j++) k[j] = ~0ull;
    for (int c = 0; c < 8; c++) {
        const u64* src = c2c + ((size_t)(b * 8 + c) * 16) * TT + t;
        for (int j = 0; j < 16; j++) {
            u64 nk = src[(size_t)j * TT];
            bool ins = nk < k[15];
            if (!__any(ins)) break;
            if (ins) kinsert(k, nk);
        }
    }
    // k sorted ascending (d, idx) == reference top_k order
#pragma unroll
    for (int j = 0; j < 16; j++)
        knn[((size_t)b * TT + t) * 16 + j] = (int)(unsigned)(k[j] & 0xffffffffull);
}

// ------- weight transpose + split-bf16 convert (mu_W1/mu_W2 -> W^T hi/lo) -------
__global__ __launch_bounds__(256) void wconv(
    const float* __restrict__ Wa, const float* __restrict__ Wb,
    unsigned short* __restrict__ Oah, unsigned short* __restrict__ Oal,
    unsigned short* __restrict__ Obh, unsigned short* __restrict__ Obl)
{
    const float* W = blockIdx.z ? Wb : Wa;
    unsigned short* Oh = blockIdx.z ? Obh : Oah;
    unsigned short* Ol = blockIdx.z ? Obl : Oal;
    __shared__ float tile[64][65];
    int tx = threadIdx.x & 63, ty = threadIdx.x >> 6;
    int n0 = blockIdx.x * 64, k0 = blockIdx.y * 64;
#pragma unroll
    for (int r = ty; r < 64; r += 4) tile[r][tx] = W[(size_t)(k0 + r) * 1024 + n0 + tx];
    __syncthreads();
#pragma unroll
    for (int r = ty; r < 64; r += 4) {
        float v = tile[tx][r];
        unsigned short hi = f2bf(v);
        Oh[(size_t)(n0 + r) * 1024 + k0 + tx] = hi;
        Ol[(size_t)(n0 + r) * 1024 + k0 + tx] = f2bf(v - bf2f(hi));
    }
}

// ============ stage A: gather + PE MLP + LN1 -> h (f32 global) ============
__global__ __launch_bounds__(256) void tok_pe(
    const float* __restrict__ x, const float* __restrict__ c1, const float* __restrict__ c2,
    const int* __restrict__ knn,
    const float* __restrict__ peW1, const float* __restrict__ peb1,
    const float* __restrict__ peW2, const float* __restrict__ peb2,
    const float* __restrict__ g1, const float* __restrict__ be1,
    float* __restrict__ hout)
{
    __shared__ float s_peW1[256], s_peb1[128], s_peW2[8192], s_peb2[64], s_g1[64], s_be1[64];
    __shared__ float s_scr[4][2352];
    int tid = threadIdx.x, lane = tid & 63, w = tid >> 6;
    if (tid < 256) s_peW1[tid] = peW1[tid];
    if (tid < 128) s_peb1[tid] = peb1[tid];
    if (tid < 64) { s_peb2[tid] = peb2[tid]; s_g1[tid] = g1[tid]; s_be1[tid] = be1[tid]; }
    for (int i = tid; i < 8192; i += 256) s_peW2[i] = peW2[i];
    __syncthreads();

    float* big = s_scr[w];
    float* sc1 = big + 2304; float* sc2 = big + 2320; float* sx = big + 2336;
    double w0a = s_peW1[lane], w1a = s_peW1[128 + lane], ba = s_peb1[lane];
    double w0b = s_peW1[64 + lane], w1b = s_peW1[192 + lane], bbv = s_peb1[64 + lane];
    double gv = (double)s_g1[lane], bv = (double)s_be1[lane];
    double pb2 = (double)s_peb2[lane];

    for (int it = 0; it < 4; ++it) {
        int tk = blockIdx.x * 16 + w * 4 + it;
        int bb = tk >> 12, tt = tk & (TT - 1);
        if (lane < 16) {
            int s = knn[(size_t)tk * 16 + lane];
            sc1[lane] = c1[((size_t)bb * SSRC + s) * TT + tt];
            sc2[lane] = c2[((size_t)bb * SSRC + s) * TT + tt];
            sx[lane]  = x[bb * SSRC + s];
        }
        WFENCE;
        // PE layer 1 (f64), gT stored f32 rows stride 18
#pragma unroll
        for (int n = 0; n < 16; n++) {
            double a_ = (double)sc1[n], b_ = (double)sc2[n];
            big[lane * 18 + n]        = (float)gelu_d(a_ * w0a + b_ * w1a + ba);
            big[(lane + 64) * 18 + n] = (float)gelu_d(a_ * w0b + b_ * w1b + bbv);
        }
        WFENCE;
        // PE layer 2 + x + LN1 (f64)
        double acc[16];
#pragma unroll
        for (int n = 0; n < 16; n++) acc[n] = pb2;
        for (int f = 0; f < 128; f++) {
            double wv = (double)s_peW2[f * 64 + lane];
#pragma unroll
            for (int n = 0; n < 16; n += 2) {
                float2 gvv = *(const float2*)&big[f * 18 + n];
                acc[n]     += (double)gvv.x * wv;
                acc[n + 1] += (double)gvv.y * wv;
            }
        }
        float* op = hout + (size_t)tk * 1024 + lane;
#pragma unroll
        for (int n = 0; n < 16; n++) {
            double v = acc[n] + (double)sx[n];
            double m = rsum64d(v) * (1.0 / 64.0);
            double d = v - m;
            double var = rsum64d(d * d) * (1.0 / 64.0);
            op[n * 64] = (float)(d / sqrt(var + 1e-5) * gv + bv);
        }
    }
}

// ============ stage B: q/k + cosine attn + WoV residual + LN2 (h in-place) ============
__global__ __launch_bounds__(256) void tok_attn(
    const float* __restrict__ x, const int* __restrict__ knn,
    const float* __restrict__ Wq, const float* __restrict__ Wk,
    const float* __restrict__ Wv, const float* __restrict__ lsc,
    const float* __restrict__ Wo, const float* __restrict__ bo,
    const float* __restrict__ g2, const float* __restrict__ be2,
    float* __restrict__ hio)
{
    __shared__ float s_Wq[4096], s_Wk[4096], s_WoV[256], s_bo[64], s_g2[64], s_be2[64];
    __shared__ float s_scr[4][2320];
    int tid = threadIdx.x, lane = tid & 63, w = tid >> 6;
    if (tid < 64) {
        s_bo[tid] = bo[tid]; s_g2[tid] = g2[tid]; s_be2[tid] = be2[tid];
        for (int hh = 0; hh < 4; hh++) {
            double a = 0.0;
            for (int hd = 0; hd < 16; hd++)
                a += (double)Wv[hh * 16 + hd] * (double)Wo[(hh * 16 + hd) * 64 + tid];
            s_WoV[hh * 64 + tid] = (float)a;
        }
    }
    for (int i = tid; i < 4096; i += 256) { s_Wq[i] = Wq[i]; s_Wk[i] = Wk[i]; }
    __syncthreads();

    int head = lane >> 4, mm = lane & 15;
    double scaleh = exp(fmin((double)lsc[head], LOG100D));
    double wov0 = (double)s_WoV[lane], wov1 = (double)s_WoV[64 + lane];
    double wov2 = (double)s_WoV[128 + lane], wov3 = (double)s_WoV[192 + lane];
    double gv = (double)s_g2[lane], bv = (double)s_be2[lane], bov = (double)s_bo[lane];
    float* big = s_scr[w];
    float* sx = big + 2304;

    for (int it = 0; it < 4; ++it) {
        int tk = blockIdx.x * 16 + w * 4 + it;
        int bb = tk >> 12;
        if (lane < 16) {
            int s = knn[(size_t)tk * 16 + lane];
            sx[lane] = x[bb * SSRC + s];
        }
        float* hp = hio + (size_t)tk * 1024 + lane;
        double h[16];
#pragma unroll
        for (int n = 0; n < 16; n++) {
            h[n] = (double)hp[n * 64];
            big[lane * 18 + n] = (float)h[n];   // hT[k=lane][n]
        }
        WFENCE;
        // q = h@Wq, k = h@Wk (f64)
        double q[16], k2[16];
#pragma unroll
        for (int n = 0; n < 16; n++) { q[n] = 0.0; k2[n] = 0.0; }
        for (int kk = 0; kk < 64; kk++) {
            double wq = (double)s_Wq[kk * 64 + lane], wk = (double)s_Wk[kk * 64 + lane];
#pragma unroll
            for (int n = 0; n < 16; n += 2) {
                float2 hv = *(const float2*)&big[kk * 18 + n];
                q[n]  += (double)hv.x * wq; q[n + 1]  += (double)hv.y * wq;
                k2[n] += (double)hv.x * wk; k2[n + 1] += (double)hv.y * wk;
            }
        }
#pragma unroll
        for (int n = 0; n < 16; n++) {
            double sq = rsum16d(q[n] * q[n]);   q[n]  /= sqrt(sq + 1e-12);
            double sk = rsum16d(k2[n] * k2[n]); k2[n] /= sqrt(sk + 1e-12);
        }
        WFENCE;   // ensure hT reads retired before overwrite
#pragma unroll
        for (int n = 0; n < 16; n++) {
            big[lane * 18 + n]        = (float)q[n];
            big[1152 + lane * 18 + n] = (float)k2[n];
        }
        WFENCE;
        // S = qn@kn^T * scale, softmax, A = att @ x
        double A_[16];
        {
            double S[16];
#pragma unroll
            for (int n = 0; n < 16; n++) S[n] = 0.0;
            for (int hd = 0; hd < 16; hd++) {
                int r = head * 16 + hd;
                double kf = (double)big[1152 + r * 18 + mm];
#pragma unroll
                for (int n = 0; n < 16; n += 2) {
                    float2 qq = *(const float2*)&big[r * 18 + n];
                    S[n] += (double)qq.x * kf; S[n + 1] += (double)qq.y * kf;
                }
            }
            double xv = (double)sx[mm];
#pragma unroll
            for (int n = 0; n < 16; n++) {
                double sv = S[n] * scaleh;
                double mx = rmax16d(sv);
                double e = exp(sv - mx);
                double se = rsum16d(e);
                A_[n] = rsum16d((e / se) * xv);
            }
        }
        // WoV residual + LN2, write back
#pragma unroll
        for (int n = 0; n < 16; n++) {
            double a0 = __shfl(A_[n], mm), a1 = __shfl(A_[n], 16 + mm);
            double a2 = __shfl(A_[n], 32 + mm), a3 = __shfl(A_[n], 48 + mm);
            double v = h[n] + a0 * wov0 + a1 * wov1 + a2 * wov2 + a3 * wov3 + bov;
            double m = rsum64d(v) * (1.0 / 64.0);
            double d = v - m;
            double var = rsum64d(d * d) * (1.0 / 64.0);
            hp[n * 64] = (float)(d / sqrt(var + 1e-5) * gv + bv);
        }
    }
}

// ============ stage C: mnh MLP + LN3 -> hn split-bf16 ============
__global__ __launch_bounds__(256) void tok_mnh(
    const float* __restrict__ hin,
    const float* __restrict__ mW1, const float* __restrict__ mb1,
    const float* __restrict__ mW2, const float* __restrict__ mb2,
    const float* __restrict__ g3, const float* __restrict__ be3,
    unsigned short* __restrict__ hnh, unsigned short* __restrict__ hnl)
{
    __shared__ float s_mW1[8192], s_mb1[128], s_mW2[128], s_g3[1024], s_be3[1024];
    __shared__ float s_scr[4][1152];
    int tid = threadIdx.x, lane = tid & 63, w = tid >> 6;
    if (tid < 128) { s_mb1[tid] = mb1[tid]; s_mW2[tid] = mW2[tid]; }
    for (int i = tid; i < 8192; i += 256) s_mW1[i] = mW1[i];
    for (int i = tid; i < 1024; i += 256) { s_g3[i] = g3[i]; s_be3[i] = be3[i]; }
    __syncthreads();

    double mb2s = (double)mb2[0];
    double mb1a = (double)s_mb1[lane], mb1b = (double)s_mb1[64 + lane];
    double w2a = (double)s_mW2[lane], w2b = (double)s_mW2[64 + lane];
    float* big = s_scr[w];

    for (int it = 0; it < 4; ++it) {
        int tk = blockIdx.x * 16 + w * 4 + it;
        const float* hp = hin + (size_t)tk * 1024 + lane;
        double h[16];
#pragma unroll
        for (int n = 0; n < 16; n++) {
            h[n] = (double)hp[n * 64];
            big[lane * 18 + n] = (float)h[n];
        }
        WFENCE;
        double t1a[16], t1b[16];
#pragma unroll
        for (int n = 0; n < 16; n++) { t1a[n] = mb1a; t1b[n] = mb1b; }
        for (int kk = 0; kk < 64; kk++) {
            double wa = (double)s_mW1[kk * 128 + lane], wb = (double)s_mW1[kk * 128 + 64 + lane];
#pragma unroll
            for (int n = 0; n < 16; n += 2) {
                float2 hv = *(const float2*)&big[kk * 18 + n];
                t1a[n] += (double)hv.x * wa; t1a[n + 1] += (double)hv.y * wa;
                t1b[n] += (double)hv.x * wb; t1b[n + 1] += (double)hv.y * wb;
            }
        }
#pragma unroll
        for (int n = 0; n < 16; n++) {
            double p = lrelu_d(t1a[n]) * w2a + lrelu_d(t1b[n]) * w2b;
            p = rsum64d(p);
            h[n] += lrelu_d(p + mb2s);
        }
        // LN3 over flattened 1024 + split-bf16 store
        double s1 = 0.0;
#pragma unroll
        for (int n = 0; n < 16; n++) s1 += h[n];
        s1 = rsum64d(s1) * (1.0 / 1024.0);
        double s2v = 0.0;
#pragma unroll
        for (int n = 0; n < 16; n++) { double d = h[n] - s1; s2v += d * d; }
        s2v = rsum64d(s2v) * (1.0 / 1024.0);
        double rs = 1.0 / sqrt(s2v + 1e-5);
        unsigned short* oph = hnh + (size_t)tk * 1024 + lane;
        unsigned short* opl = hnl + (size_t)tk * 1024 + lane;
#pragma unroll
        for (int n = 0; n < 16; n++) {
            double v = (h[n] - s1) * rs * (double)s_g3[n * 64 + lane] + (double)s_be3[n * 64 + lane];
            unsigned short hi = f2bf((float)v);
            oph[n * 64] = hi;
            opl[n * 64] = f2bf((float)(v - (double)bf2f(hi)));
        }
    }
}

// ------- split-bf16 MFMA GEMM: out = lrelu(A@B + bias), A=Ah+Al, B=Bh+Bl -------
#define AH_OFF 0
#define AL_OFF 4096
#define BH_OFF 8192
#define BL_OFF 12288
template<int OUTSPLIT>
__global__ __launch_bounds__(256) void gemm_split(
    const unsigned short* __restrict__ Ah, const unsigned short* __restrict__ Al,
    const unsigned short* __restrict__ Bh, const unsigned short* __restrict__ Bl,
    const float* __restrict__ bias,
    unsigned short* __restrict__ oh, unsigned short* __restrict__ ol,
    float* __restrict__ of, int M, int N, int K)
{
    __shared__ unsigned short SM[16384];
    int tid = threadIdx.x, lane = tid & 63, w = tid >> 6;
    int wm = w >> 1, wn = w & 1;
    int m0 = blockIdx.y * 128, n0 = blockIdx.x * 128;
    f32x4 acc[4][4];
#pragma unroll
    for (int i = 0; i < 4; i++)
#pragma unroll
        for (int j = 0; j < 4; j++) acc[i][j] = (f32x4){0.f, 0.f, 0.f, 0.f};
    int row = tid >> 2, c8 = (tid & 3) * 8;
    size_t aoff = (size_t)(m0 + row) * K + c8;
    size_t boff = (size_t)(n0 + row) * K + c8;
    for (int kk = 0; kk < K; kk += 32) {
        __syncthreads();
        GLDS16(Ah + aoff + kk,                   SM + AH_OFF + tid * 8);
        GLDS16(Ah + aoff + (size_t)64 * K + kk,  SM + AH_OFF + 2048 + tid * 8);
        GLDS16(Al + aoff + kk,                   SM + AL_OFF + tid * 8);
        GLDS16(Al + aoff + (size_t)64 * K + kk,  SM + AL_OFF + 2048 + tid * 8);
        GLDS16(Bh + boff + kk,                   SM + BH_OFF + tid * 8);
        GLDS16(Bh + boff + (size_t)64 * K + kk,  SM + BH_OFF + 2048 + tid * 8);
        GLDS16(Bl + boff + kk,                   SM + BL_OFF + tid * 8);
        GLDS16(Bl + boff + (size_t)64 * K + kk,  SM + BL_OFF + 2048 + tid * 8);
        asm volatile("s_waitcnt vmcnt(0)" ::: "memory");
        __syncthreads();
        int kh = (lane >> 4) * 8, rA = wm * 64 + (lane & 15), rB = wn * 64 + (lane & 15);
        s16x8 afh[4], afl[4], bfh[4], bfl[4];
#pragma unroll
        for (int i = 0; i < 4; i++) {
            afh[i] = *(const s16x8*)&SM[AH_OFF + (rA + i * 16) * 32 + kh];
            afl[i] = *(const s16x8*)&SM[AL_OFF + (rA + i * 16) * 32 + kh];
            bfh[i] = *(const s16x8*)&SM[BH_OFF + (rB + i * 16) * 32 + kh];
            bfl[i] = *(const s16x8*)&SM[BL_OFF + (rB + i * 16) * 32 + kh];
        }
#pragma unroll
        for (int i = 0; i < 4; i++)
#pragma unroll
            for (int j = 0; j < 4; j++) {
                acc[i][j] = __builtin_amdgcn_mfma_f32_16x16x32_bf16(afl[i], bfh[j], acc[i][j], 0, 0, 0);
                acc[i][j] = __builtin_amdgcn_mfma_f32_16x16x32_bf16(afh[i], bfl[j], acc[i][j], 0, 0, 0);
                acc[i][j] = __builtin_amdgcn_mfma_f32_16x16x32_bf16(afh[i], bfh[j], acc[i][j], 0, 0, 0);
            }
    }
    float bc[4];
#pragma unroll
    for (int j = 0; j < 4; j++) bc[j] = bias[n0 + wn * 64 + j * 16 + (lane & 15)];
#pragma unroll
    for (int i = 0; i < 4; i++) {
#pragma unroll
        for (int j = 0; j < 4; j++) {
#pragma unroll
            for (int r = 0; r < 4; r++) {
                int rw = m0 + wm * 64 + i * 16 + (lane >> 4) * 4 + r;
                int cl = n0 + wn * 64 + j * 16 + (lane & 15);
                float v = acc[i][j][r] + bc[j];
                v = v >= 0.f ? v : 0.2f * v;
                if (OUTSPLIT) {
                    unsigned short hi = f2bf(v);
                    oh[(size_t)rw * N + cl] = hi;
                    ol[(size_t)rw * N + cl] = f2bf(v - bf2f(hi));
                } else {
                    of[(size_t)rw * N + cl] = v;
                }
            }
        }
    }
}

extern "C" void kernel_launch(void* const* d_in, const int* in_sizes, int n_in,
                              void* d_out, int out_size, void* d_ws, size_t ws_size,
                              hipStream_t stream)
{
    const float* x    = (const float*)d_in[0];
    const float* c1   = (const float*)d_in[1];
    const float* c2   = (const float*)d_in[2];
    const float* peW1 = (const float*)d_in[3];
    const float* peb1 = (const float*)d_in[4];
    const float* peW2 = (const float*)d_in[5];
    const float* peb2 = (const float*)d_in[6];
    const float* Wq   = (const float*)d_in[7];
    const float* Wk   = (const float*)d_in[8];
    const float* Wv   = (const float*)d_in[9];
    const float* lsc  = (const float*)d_in[10];
    const float* Wo   = (const float*)d_in[11];
    const float* bo   = (const float*)d_in[12];
    const float* g1   = (const float*)d_in[13];
    const float* be1  = (const float*)d_in[14];
    const float* g2   = (const float*)d_in[15];
    const float* be2  = (const float*)d_in[16];
    const float* g3   = (const float*)d_in[17];
    const float* be3  = (const float*)d_in[18];
    const float* mW1  = (const float*)d_in[19];
    const float* mb1  = (const float*)d_in[20];
    const float* mW2  = (const float*)d_in[21];
    const float* mb2  = (const float*)d_in[22];
    const float* muW1 = (const float*)d_in[23];
    const float* mub1 = (const float*)d_in[24];
    const float* muW2 = (const float*)d_in[25];
    const float* mub2 = (const float*)d_in[26];

    const size_t MB = (size_t)1 << 20;
    char* ws = (char*)d_ws;
    // Timeline-safe layout, 80.5 MiB total:
    //  [0,64M)   cand (u64, dead after merge1) -> hbuf[0,32M) -> y1h[0,16M)+y1l[16,32M)
    //  [32,64M)  hnh[32,48M) + hnl[48,64M)  (written by tok_mnh after cand dead)
    //  [64,72M)  c2c (dead after merge2)
    //  [72,80M)  w1th/w1tl/w2th/w2tl
    //  [80,80.5M) knn
    u64*            cand   = (u64*)(ws);
    float*          hbuf   = (float*)(ws);
    unsigned short* y1h    = (unsigned short*)(ws);
    unsigned short* y1l    = (unsigned short*)(ws + 16 * MB);
    unsigned short* hnh    = (unsigned short*)(ws + 32 * MB);
    unsigned short* hnl    = (unsigned short*)(ws + 48 * MB);
    u64*            c2c    = (u64*)(ws + 64 * MB);
    unsigned short* w1th   = (unsigned short*)(ws + 72 * MB);
    unsigned short* w1tl   = (unsigned short*)(ws + 74 * MB);
    unsigned short* w2th   = (unsigned short*)(ws + 76 * MB);
    unsigned short* w2tl   = (unsigned short*)(ws + 78 * MB);
    int*            knn    = (int*)(ws + 80 * MB);
    (void)in_sizes; (void)n_in; (void)out_size; (void)ws_size;

    wconv<<<dim3(16, 16, 2), 256, 0, stream>>>(muW1, muW2, w1th, w1tl, w2th, w2tl);
    topk_partial<<<dim3(TT / 256, NC, B_), 256, 0, stream>>>(c1, c2, cand);
    topk_merge1<<<dim3(TT / 64, 8, B_), 64, 0, stream>>>(cand, c2c);
    topk_merge2<<<dim3(TT / 64, B_), 64, 0, stream>>>(c2c, knn);
    tok_pe<<<dim3(512), 256, 0, stream>>>(x, c1, c2, knn, peW1, peb1, peW2, peb2, g1, be1, hbuf);
    tok_attn<<<dim3(512), 256, 0, stream>>>(x, knn, Wq, Wk, Wv, lsc, Wo, bo, g2, be2, hbuf);
    tok_mnh<<<dim3(512), 256, 0, stream>>>(hbuf, mW1, mb1, mW2, mb2, g3, be3, hnh, hnl);
    gemm_split<1><<<dim3(8, 64), 256, 0, stream>>>(hnh, hnl, w1th, w1tl, mub1,
                                                   y1h, y1l, (float*)nullptr, 8192, 1024, 1024);
    gemm_split<0><<<dim3(8, 64), 256, 0, stream>>>(y1h, y1l, w2th, w2tl, mub2,
                                                   (unsigned short*)nullptr, (unsigned short*)nullptr,
                                                   (float*)d_out, 8192, 1024, 1024);
}

// Round 6
// 777.701 us; speedup vs baseline: 2.1835x; 1.1488x over previous
//
#include <hip/hip_runtime.h>
#include <hip/hip_bf16.h>

#define B_    2
#define SSRC  8192
#define TT    4096
#define NHN   16
#define NC    64
#define CS    128           // SSRC / NC
#define LOG100D 4.605170185988091368035982909368

typedef short s16x8 __attribute__((ext_vector_type(8)));
typedef float f32x4 __attribute__((ext_vector_type(4)));
typedef unsigned long long u64;

typedef const __attribute__((address_space(1))) void* gas_ptr;
typedef __attribute__((address_space(3))) void* las_ptr;
#define GLDS16(g, l) __builtin_amdgcn_global_load_lds((gas_ptr)(g), (las_ptr)(l), 16, 0, 0)

// wave-local LDS fence: scratch is per-wave, no cross-wave barrier needed
#define WFENCE asm volatile("s_waitcnt lgkmcnt(0)" ::: "memory")

__device__ __forceinline__ unsigned short f2bf(float f) {
    unsigned u = __float_as_uint(f);
    u = u + 0x7fffu + ((u >> 16) & 1u);
    return (unsigned short)(u >> 16);
}
__device__ __forceinline__ float bf2f(unsigned short h) {
    return __uint_as_float(((unsigned)h) << 16);
}
__device__ __forceinline__ double lrelu_d(double v) { return v >= 0.0 ? v : 0.2 * v; }
__device__ __forceinline__ double gelu_d(double u) {
    double a = 0.7978845608028654 * (u + 0.044715 * u * u * u);
    return 0.5 * u * (1.0 + tanh(a));
}
__device__ __forceinline__ double rsum16d(double v) {
    v += __shfl_xor(v, 1); v += __shfl_xor(v, 2);
    v += __shfl_xor(v, 4); v += __shfl_xor(v, 8);
    return v;
}
__device__ __forceinline__ double rmax16d(double v) {
    v = fmax(v, __shfl_xor(v, 1)); v = fmax(v, __shfl_xor(v, 2));
    v = fmax(v, __shfl_xor(v, 4)); v = fmax(v, __shfl_xor(v, 8));
    return v;
}
__device__ __forceinline__ double rsum64d(double v) {
    v += __shfl_xor(v, 1); v += __shfl_xor(v, 2); v += __shfl_xor(v, 4);
    v += __shfl_xor(v, 8); v += __shfl_xor(v, 16); v += __shfl_xor(v, 32);
    return v;
}

// ---- branch-free 16-element sorting primitives (u64 keys, static reg indices) ----
__device__ __forceinline__ void ce(u64 &a, u64 &b) {
    bool c = a < b; u64 lo = c ? a : b; u64 hi = c ? b : a; a = lo; b = hi;
}
// Batcher merge-exchange sort, 63 CEs, ascending
__device__ __forceinline__ void sort16(u64 (&k)[16]) {
    ce(k[0],k[8]); ce(k[1],k[9]); ce(k[2],k[10]); ce(k[3],k[11]);
    ce(k[4],k[12]); ce(k[5],k[13]); ce(k[6],k[14]); ce(k[7],k[15]);
    ce(k[0],k[4]); ce(k[1],k[5]); ce(k[2],k[6]); ce(k[3],k[7]);
    ce(k[8],k[12]); ce(k[9],k[13]); ce(k[10],k[14]); ce(k[11],k[15]);
    ce(k[4],k[8]); ce(k[5],k[9]); ce(k[6],k[10]); ce(k[7],k[11]);
    ce(k[0],k[2]); ce(k[1],k[3]); ce(k[4],k[6]); ce(k[5],k[7]);
    ce(k[8],k[10]); ce(k[9],k[11]); ce(k[12],k[14]); ce(k[13],k[15]);
    ce(k[2],k[8]); ce(k[3],k[9]); ce(k[6],k[12]); ce(k[7],k[13]);
    ce(k[2],k[4]); ce(k[3],k[5]); ce(k[6],k[8]); ce(k[7],k[9]);
    ce(k[10],k[12]); ce(k[11],k[13]);
    ce(k[0],k[1]); ce(k[2],k[3]); ce(k[4],k[5]); ce(k[6],k[7]);
    ce(k[8],k[9]); ce(k[10],k[11]); ce(k[12],k[13]); ce(k[14],k[15]);
    ce(k[1],k[8]); ce(k[3],k[10]); ce(k[5],k[12]); ce(k[7],k[14]);
    ce(k[1],k[4]); ce(k[3],k[6]); ce(k[5],k[8]); ce(k[7],k[10]);
    ce(k[9],k[12]); ce(k[11],k[14]);
    ce(k[1],k[2]); ce(k[3],k[4]); ce(k[5],k[6]); ce(k[7],k[8]);
    ce(k[9],k[10]); ce(k[11],k[12]); ce(k[13],k[14]);
}
// bitonic merge of a unimodal (asc-then-desc) 16-seq -> sorted asc, 32 CEs
__device__ __forceinline__ void bmerge16(u64 (&k)[16]) {
    ce(k[0],k[8]); ce(k[1],k[9]); ce(k[2],k[10]); ce(k[3],k[11]);
    ce(k[4],k[12]); ce(k[5],k[13]); ce(k[6],k[14]); ce(k[7],k[15]);
    ce(k[0],k[4]); ce(k[1],k[5]); ce(k[2],k[6]); ce(k[3],k[7]);
    ce(k[8],k[12]); ce(k[9],k[13]); ce(k[10],k[14]); ce(k[11],k[15]);
    ce(k[0],k[2]); ce(k[1],k[3]); ce(k[4],k[6]); ce(k[5],k[7]);
    ce(k[8],k[10]); ce(k[9],k[11]); ce(k[12],k[14]); ce(k[13],k[15]);
    ce(k[0],k[1]); ce(k[2],k[3]); ce(k[4],k[5]); ce(k[6],k[7]);
    ce(k[8],k[9]); ce(k[10],k[11]); ce(k[12],k[13]); ce(k[14],k[15]);
}
// keep 16 smallest of sorted L and sorted B (both asc); L out sorted asc
__device__ __forceinline__ void merge_keep16(u64 (&L)[16], const u64 (&B)[16]) {
#pragma unroll
    for (int i = 0; i < 16; i++) { u64 bb = B[15 - i]; L[i] = L[i] < bb ? L[i] : bb; }
    bmerge16(L);
}

// ---------------- top-k phase A: per-chunk sorted top-16 (batch-bitonic) ----------------
__global__ __launch_bounds__(256) void topk_partial(
    const float* __restrict__ c1, const float* __restrict__ c2,
    u64* __restrict__ cand)
{
    int t = blockIdx.x * 256 + threadIdx.x;
    int ch = blockIdx.y, b = blockIdx.z;
    const float* p1 = c1 + ((size_t)b * SSRC + (size_t)ch * CS) * TT + t;
    const float* p2 = c2 + ((size_t)b * SSRC + (size_t)ch * CS) * TT + t;
    u64 k[16];
#pragma unroll
    for (int j = 0; j < 16; j++) k[j] = ~0ull;
    int sbase = ch * CS;
    for (int s = 0; s < CS; s += 16) {
        u64 bt[16];
#pragma unroll
        for (int u = 0; u < 16; u++) {
            float a_ = p1[(size_t)(s + u) * TT];
            float b_ = p2[(size_t)(s + u) * TT];
            // exact IEEE mul/add to match numpy f32 (no fma contraction)
            float dd = __fadd_rn(__fmul_rn(a_, a_), __fmul_rn(b_, b_));
            bt[u] = ((u64)__float_as_uint(dd) << 32) | (unsigned)(sbase + s + u);
        }
        sort16(bt);
        merge_keep16(k, bt);
    }
    u64* dst = cand + ((size_t)(b * NC + ch) * 16) * TT + t;
#pragma unroll
    for (int j = 0; j < 16; j++) dst[(size_t)j * TT] = k[j];
}

// ---------------- top-k merge level 1: 64 chunk-lists -> 8 group-lists ----------------
__global__ __launch_bounds__(64) void topk_merge1(
    const u64* __restrict__ cand, u64* __restrict__ c2c)
{
    int t = blockIdx.x * 64 + threadIdx.x;
    int g = blockIdx.y, b = blockIdx.z;
    u64 k[16];
#pragma unroll
    for (int j = 0; j < 16; j++) k[j] = ~0ull;
    for (int c = g * 8; c < g * 8 + 8; c++) {
        const u64* src = cand + ((size_t)(b * NC + c) * 16) * TT + t;
        u64 bt[16];
#pragma unroll
        for (int j = 0; j < 16; j++) bt[j] = src[(size_t)j * TT];
        merge_keep16(k, bt);
    }
    u64* dst = c2c + ((size_t)((b * 8 + g) * 16)) * TT + t;
#pragma unroll
    for (int j = 0; j < 16; j++) dst[(size_t)j * TT] = k[j];
}

// ---------------- top-k merge level 2: 8 lists -> sorted knn indices ----------------
__global__ __launch_bounds__(64) void topk_merge2(
    const u64* __restrict__ c2c, int* __restrict__ knn)
{
    int t = blockIdx.x * 64 + threadIdx.x;
    int b = blockIdx.y;
    u64 k[16];
#pragma unroll
    for (int j = 0; j < 16; j++) k[j] = ~0ull;
    for (int c = 0; c < 8; c++) {
        const u64* src = c2c + ((size_t)(b * 8 + c) * 16) * TT + t;
        u64 bt[16];
#pragma unroll
        for (int j = 0; j < 16; j++) bt[j] = src[(size_t)j * TT];
        merge_keep16(k, bt);
    }
    // k sorted ascending (d, idx) == reference top_k order
#pragma unroll
    for (int j = 0; j < 16; j++)
        knn[((size_t)b * TT + t) * 16 + j] = (int)(unsigned)(k[j] & 0xffffffffull);
}

// ------- weight transpose + split-bf16 convert (mu_W1/mu_W2 -> W^T hi/lo) -------
__global__ __launch_bounds__(256) void wconv(
    const float* __restrict__ Wa, const float* __restrict__ Wb,
    unsigned short* __restrict__ Oah, unsigned short* __restrict__ Oal,
    unsigned short* __restrict__ Obh, unsigned short* __restrict__ Obl)
{
    const float* W = blockIdx.z ? Wb : Wa;
    unsigned short* Oh = blockIdx.z ? Obh : Oah;
    unsigned short* Ol = blockIdx.z ? Obl : Oal;
    __shared__ float tile[64][65];
    int tx = threadIdx.x & 63, ty = threadIdx.x >> 6;
    int n0 = blockIdx.x * 64, k0 = blockIdx.y * 64;
#pragma unroll
    for (int r = ty; r < 64; r += 4) tile[r][tx] = W[(size_t)(k0 + r) * 1024 + n0 + tx];
    __syncthreads();
#pragma unroll
    for (int r = ty; r < 64; r += 4) {
        float v = tile[tx][r];
        unsigned short hi = f2bf(v);
        Oh[(size_t)(n0 + r) * 1024 + k0 + tx] = hi;
        Ol[(size_t)(n0 + r) * 1024 + k0 + tx] = f2bf(v - bf2f(hi));
    }
}

// ============ stage A: gather + PE MLP + LN1 -> h (f32 global) ============
__global__ __launch_bounds__(256) void tok_pe(
    const float* __restrict__ x, const float* __restrict__ c1, const float* __restrict__ c2,
    const int* __restrict__ knn,
    const float* __restrict__ peW1, const float* __restrict__ peb1,
    const float* __restrict__ peW2, const float* __restrict__ peb2,
    const float* __restrict__ g1, const float* __restrict__ be1,
    float* __restrict__ hout)
{
    __shared__ float s_peW1[256], s_peb1[128], s_peW2[8192], s_peb2[64], s_g1[64], s_be1[64];
    __shared__ float s_scr[4][2352];
    int tid = threadIdx.x, lane = tid & 63, w = tid >> 6;
    if (tid < 256) s_peW1[tid] = peW1[tid];
    if (tid < 128) s_peb1[tid] = peb1[tid];
    if (tid < 64) { s_peb2[tid] = peb2[tid]; s_g1[tid] = g1[tid]; s_be1[tid] = be1[tid]; }
    for (int i = tid; i < 8192; i += 256) s_peW2[i] = peW2[i];
    __syncthreads();

    float* big = s_scr[w];
    float* sc1 = big + 2304; float* sc2 = big + 2320; float* sx = big + 2336;
    double w0a = s_peW1[lane], w1a = s_peW1[128 + lane], ba = s_peb1[lane];
    double w0b = s_peW1[64 + lane], w1b = s_peW1[192 + lane], bbv = s_peb1[64 + lane];
    double gv = (double)s_g1[lane], bv = (double)s_be1[lane];
    double pb2 = (double)s_peb2[lane];

    for (int it = 0; it < 4; ++it) {
        int tk = blockIdx.x * 16 + w * 4 + it;
        int bb = tk >> 12, tt = tk & (TT - 1);
        if (lane < 16) {
            int s = knn[(size_t)tk * 16 + lane];
            sc1[lane] = c1[((size_t)bb * SSRC + s) * TT + tt];
            sc2[lane] = c2[((size_t)bb * SSRC + s) * TT + tt];
            sx[lane]  = x[bb * SSRC + s];
        }
        WFENCE;
        // PE layer 1 (f64), gT stored f32 rows stride 18
#pragma unroll
        for (int n = 0; n < 16; n++) {
            double a_ = (double)sc1[n], b_ = (double)sc2[n];
            big[lane * 18 + n]        = (float)gelu_d(a_ * w0a + b_ * w1a + ba);
            big[(lane + 64) * 18 + n] = (float)gelu_d(a_ * w0b + b_ * w1b + bbv);
        }
        WFENCE;
        // PE layer 2 + x + LN1 (f64)
        double acc[16];
#pragma unroll
        for (int n = 0; n < 16; n++) acc[n] = pb2;
        for (int f = 0; f < 128; f++) {
            double wv = (double)s_peW2[f * 64 + lane];
#pragma unroll
            for (int n = 0; n < 16; n += 2) {
                float2 gvv = *(const float2*)&big[f * 18 + n];
                acc[n]     += (double)gvv.x * wv;
                acc[n + 1] += (double)gvv.y * wv;
            }
        }
        float* op = hout + (size_t)tk * 1024 + lane;
#pragma unroll
        for (int n = 0; n < 16; n++) {
            double v = acc[n] + (double)sx[n];
            double m = rsum64d(v) * (1.0 / 64.0);
            double d = v - m;
            double var = rsum64d(d * d) * (1.0 / 64.0);
            op[n * 64] = (float)(d / sqrt(var + 1e-5) * gv + bv);
        }
    }
}

// ============ stage B: q/k + cosine attn + WoV residual + LN2 (h in-place) ============
__global__ __launch_bounds__(256) void tok_attn(
    const float* __restrict__ x, const int* __restrict__ knn,
    const float* __restrict__ Wq, const float* __restrict__ Wk,
    const float* __restrict__ Wv, const float* __restrict__ lsc,
    const float* __restrict__ Wo, const float* __restrict__ bo,
    const float* __restrict__ g2, const float* __restrict__ be2,
    float* __restrict__ hio)
{
    __shared__ float s_Wq[4096], s_Wk[4096], s_WoV[256], s_bo[64], s_g2[64], s_be2[64];
    __shared__ float s_scr[4][2320];
    int tid = threadIdx.x, lane = tid & 63, w = tid >> 6;
    if (tid < 64) {
        s_bo[tid] = bo[tid]; s_g2[tid] = g2[tid]; s_be2[tid] = be2[tid];
        for (int hh = 0; hh < 4; hh++) {
            double a = 0.0;
            for (int hd = 0; hd < 16; hd++)
                a += (double)Wv[hh * 16 + hd] * (double)Wo[(hh * 16 + hd) * 64 + tid];
            s_WoV[hh * 64 + tid] = (float)a;
        }
    }
    for (int i = tid; i < 4096; i += 256) { s_Wq[i] = Wq[i]; s_Wk[i] = Wk[i]; }
    __syncthreads();

    int head = lane >> 4, mm = lane & 15;
    double scaleh = exp(fmin((double)lsc[head], LOG100D));
    double wov0 = (double)s_WoV[lane], wov1 = (double)s_WoV[64 + lane];
    double wov2 = (double)s_WoV[128 + lane], wov3 = (double)s_WoV[192 + lane];
    double gv = (double)s_g2[lane], bv = (double)s_be2[lane], bov = (double)s_bo[lane];
    float* big = s_scr[w];
    float* sx = big + 2304;

    for (int it = 0; it < 4; ++it) {
        int tk = blockIdx.x * 16 + w * 4 + it;
        int bb = tk >> 12;
        if (lane < 16) {
            int s = knn[(size_t)tk * 16 + lane];
            sx[lane] = x[bb * SSRC + s];
        }
        float* hp = hio + (size_t)tk * 1024 + lane;
        double h[16];
#pragma unroll
        for (int n = 0; n < 16; n++) {
            h[n] = (double)hp[n * 64];
            big[lane * 18 + n] = (float)h[n];   // hT[k=lane][n]
        }
        WFENCE;
        // q = h@Wq, k = h@Wk (f64)
        double q[16], k2[16];
#pragma unroll
        for (int n = 0; n < 16; n++) { q[n] = 0.0; k2[n] = 0.0; }
        for (int kk = 0; kk < 64; kk++) {
            double wq = (double)s_Wq[kk * 64 + lane], wk = (double)s_Wk[kk * 64 + lane];
#pragma unroll
            for (int n = 0; n < 16; n += 2) {
                float2 hv = *(const float2*)&big[kk * 18 + n];
                q[n]  += (double)hv.x * wq; q[n + 1]  += (double)hv.y * wq;
                k2[n] += (double)hv.x * wk; k2[n + 1] += (double)hv.y * wk;
            }
        }
#pragma unroll
        for (int n = 0; n < 16; n++) {
            double sq = rsum16d(q[n] * q[n]);   q[n]  /= sqrt(sq + 1e-12);
            double sk = rsum16d(k2[n] * k2[n]); k2[n] /= sqrt(sk + 1e-12);
        }
        WFENCE;   // ensure hT reads retired before overwrite
#pragma unroll
        for (int n = 0; n < 16; n++) {
            big[lane * 18 + n]        = (float)q[n];
            big[1152 + lane * 18 + n] = (float)k2[n];
        }
        WFENCE;
        // S = qn@kn^T * scale, softmax, A = att @ x
        double A_[16];
        {
            double S[16];
#pragma unroll
            for (int n = 0; n < 16; n++) S[n] = 0.0;
            for (int hd = 0; hd < 16; hd++) {
                int r = head * 16 + hd;
                double kf = (double)big[1152 + r * 18 + mm];
#pragma unroll
                for (int n = 0; n < 16; n += 2) {
                    float2 qq = *(const float2*)&big[r * 18 + n];
                    S[n] += (double)qq.x * kf; S[n + 1] += (double)qq.y * kf;
                }
            }
            double xv = (double)sx[mm];
#pragma unroll
            for (int n = 0; n < 16; n++) {
                double sv = S[n] * scaleh;
                double mx = rmax16d(sv);
                double e = exp(sv - mx);
                double se = rsum16d(e);
                A_[n] = rsum16d((e / se) * xv);
            }
        }
        // WoV residual + LN2, write back
#pragma unroll
        for (int n = 0; n < 16; n++) {
            double a0 = __shfl(A_[n], mm), a1 = __shfl(A_[n], 16 + mm);
            double a2 = __shfl(A_[n], 32 + mm), a3 = __shfl(A_[n], 48 + mm);
            double v = h[n] + a0 * wov0 + a1 * wov1 + a2 * wov2 + a3 * wov3 + bov;
            double m = rsum64d(v) * (1.0 / 64.0);
            double d = v - m;
            double var = rsum64d(d * d) * (1.0 / 64.0);
            hp[n * 64] = (float)(d / sqrt(var + 1e-5) * gv + bv);
        }
    }
}

// ============ stage C: mnh MLP + LN3 -> hn split-bf16 ============
__global__ __launch_bounds__(256) void tok_mnh(
    const float* __restrict__ hin,
    const float* __restrict__ mW1, const float* __restrict__ mb1,
    const float* __restrict__ mW2, const float* __restrict__ mb2,
    const float* __restrict__ g3, const float* __restrict__ be3,
    unsigned short* __restrict__ hnh, unsigned short* __restrict__ hnl)
{
    __shared__ float s_mW1[8192], s_mb1[128], s_mW2[128], s_g3[1024], s_be3[1024];
    __shared__ float s_scr[4][1152];
    int tid = threadIdx.x, lane = tid & 63, w = tid >> 6;
    if (tid < 128) { s_mb1[tid] = mb1[tid]; s_mW2[tid] = mW2[tid]; }
    for (int i = tid; i < 8192; i += 256) s_mW1[i] = mW1[i];
    for (int i = tid; i < 1024; i += 256) { s_g3[i] = g3[i]; s_be3[i] = be3[i]; }
    __syncthreads();

    double mb2s = (double)mb2[0];
    double mb1a = (double)s_mb1[lane], mb1b = (double)s_mb1[64 + lane];
    double w2a = (double)s_mW2[lane], w2b = (double)s_mW2[64 + lane];
    float* big = s_scr[w];

    for (int it = 0; it < 4; ++it) {
        int tk = blockIdx.x * 16 + w * 4 + it;
        const float* hp = hin + (size_t)tk * 1024 + lane;
        double h[16];
#pragma unroll
        for (int n = 0; n < 16; n++) {
            h[n] = (double)hp[n * 64];
            big[lane * 18 + n] = (float)h[n];
        }
        WFENCE;
        double t1a[16], t1b[16];
#pragma unroll
        for (int n = 0; n < 16; n++) { t1a[n] = mb1a; t1b[n] = mb1b; }
        for (int kk = 0; kk < 64; kk++) {
            double wa = (double)s_mW1[kk * 128 + lane], wb = (double)s_mW1[kk * 128 + 64 + lane];
#pragma unroll
            for (int n = 0; n < 16; n += 2) {
                float2 hv = *(const float2*)&big[kk * 18 + n];
                t1a[n] += (double)hv.x * wa; t1a[n + 1] += (double)hv.y * wa;
                t1b[n] += (double)hv.x * wb; t1b[n + 1] += (double)hv.y * wb;
            }
        }
#pragma unroll
        for (int n = 0; n < 16; n++) {
            double p = lrelu_d(t1a[n]) * w2a + lrelu_d(t1b[n]) * w2b;
            p = rsum64d(p);
            h[n] += lrelu_d(p + mb2s);
        }
        // LN3 over flattened 1024 + split-bf16 store
        double s1 = 0.0;
#pragma unroll
        for (int n = 0; n < 16; n++) s1 += h[n];
        s1 = rsum64d(s1) * (1.0 / 1024.0);
        double s2v = 0.0;
#pragma unroll
        for (int n = 0; n < 16; n++) { double d = h[n] - s1; s2v += d * d; }
        s2v = rsum64d(s2v) * (1.0 / 1024.0);
        double rs = 1.0 / sqrt(s2v + 1e-5);
        unsigned short* oph = hnh + (size_t)tk * 1024 + lane;
        unsigned short* opl = hnl + (size_t)tk * 1024 + lane;
#pragma unroll
        for (int n = 0; n < 16; n++) {
            double v = (h[n] - s1) * rs * (double)s_g3[n * 64 + lane] + (double)s_be3[n * 64 + lane];
            unsigned short hi = f2bf((float)v);
            oph[n * 64] = hi;
            opl[n * 64] = f2bf((float)(v - (double)bf2f(hi)));
        }
    }
}

// ------- split-bf16 MFMA GEMM: out = lrelu(A@B + bias), A=Ah+Al, B=Bh+Bl -------
#define AH_OFF 0
#define AL_OFF 4096
#define BH_OFF 8192
#define BL_OFF 12288
template<int OUTSPLIT>
__global__ __launch_bounds__(256) void gemm_split(
    const unsigned short* __restrict__ Ah, const unsigned short* __restrict__ Al,
    const unsigned short* __restrict__ Bh, const unsigned short* __restrict__ Bl,
    const float* __restrict__ bias,
    unsigned short* __restrict__ oh, unsigned short* __restrict__ ol,
    float* __restrict__ of, int M, int N, int K)
{
    __shared__ unsigned short SM[16384];
    int tid = threadIdx.x, lane = tid & 63, w = tid >> 6;
    int wm = w >> 1, wn = w & 1;
    int m0 = blockIdx.y * 128, n0 = blockIdx.x * 128;
    f32x4 acc[4][4];
#pragma unroll
    for (int i = 0; i < 4; i++)
#pragma unroll
        for (int j = 0; j < 4; j++) acc[i][j] = (f32x4){0.f, 0.f, 0.f, 0.f};
    int row = tid >> 2, c8 = (tid & 3) * 8;
    size_t aoff = (size_t)(m0 + row) * K + c8;
    size_t boff = (size_t)(n0 + row) * K + c8;
    for (int kk = 0; kk < K; kk += 32) {
        __syncthreads();
        GLDS16(Ah + aoff + kk,                   SM + AH_OFF + tid * 8);
        GLDS16(Ah + aoff + (size_t)64 * K + kk,  SM + AH_OFF + 2048 + tid * 8);
        GLDS16(Al + aoff + kk,                   SM + AL_OFF + tid * 8);
        GLDS16(Al + aoff + (size_t)64 * K + kk,  SM + AL_OFF + 2048 + tid * 8);
        GLDS16(Bh + boff + kk,                   SM + BH_OFF + tid * 8);
        GLDS16(Bh + boff + (size_t)64 * K + kk,  SM + BH_OFF + 2048 + tid * 8);
        GLDS16(Bl + boff + kk,                   SM + BL_OFF + tid * 8);
        GLDS16(Bl + boff + (size_t)64 * K + kk,  SM + BL_OFF + 2048 + tid * 8);
        asm volatile("s_waitcnt vmcnt(0)" ::: "memory");
        __syncthreads();
        int kh = (lane >> 4) * 8, rA = wm * 64 + (lane & 15), rB = wn * 64 + (lane & 15);
        s16x8 afh[4], afl[4], bfh[4], bfl[4];
#pragma unroll
        for (int i = 0; i < 4; i++) {
            afh[i] = *(const s16x8*)&SM[AH_OFF + (rA + i * 16) * 32 + kh];
            afl[i] = *(const s16x8*)&SM[AL_OFF + (rA + i * 16) * 32 + kh];
            bfh[i] = *(const s16x8*)&SM[BH_OFF + (rB + i * 16) * 32 + kh];
            bfl[i] = *(const s16x8*)&SM[BL_OFF + (rB + i * 16) * 32 + kh];
        }
#pragma unroll
        for (int i = 0; i < 4; i++)
#pragma unroll
            for (int j = 0; j < 4; j++) {
                acc[i][j] = __builtin_amdgcn_mfma_f32_16x16x32_bf16(afl[i], bfh[j], acc[i][j], 0, 0, 0);
                acc[i][j] = __builtin_amdgcn_mfma_f32_16x16x32_bf16(afh[i], bfl[j], acc[i][j], 0, 0, 0);
                acc[i][j] = __builtin_amdgcn_mfma_f32_16x16x32_bf16(afh[i], bfh[j], acc[i][j], 0, 0, 0);
            }
    }
    float bc[4];
#pragma unroll
    for (int j = 0; j < 4; j++) bc[j] = bias[n0 + wn * 64 + j * 16 + (lane & 15)];
#pragma unroll
    for (int i = 0; i < 4; i++) {
#pragma unroll
        for (int j = 0; j < 4; j++) {
#pragma unroll
            for (int r = 0; r < 4; r++) {
                int rw = m0 + wm * 64 + i * 16 + (lane >> 4) * 4 + r;
                int cl = n0 + wn * 64 + j * 16 + (lane & 15);
                float v = acc[i][j][r] + bc[j];
                v = v >= 0.f ? v : 0.2f * v;
                if (OUTSPLIT) {
                    unsigned short hi = f2bf(v);
                    oh[(size_t)rw * N + cl] = hi;
                    ol[(size_t)rw * N + cl] = f2bf(v - bf2f(hi));
                } else {
                    of[(size_t)rw * N + cl] = v;
                }
            }
        }
    }
}

extern "C" void kernel_launch(void* const* d_in, const int* in_sizes, int n_in,
                              void* d_out, int out_size, void* d_ws, size_t ws_size,
                              hipStream_t stream)
{
    const float* x    = (const float*)d_in[0];
    const float* c1   = (const float*)d_in[1];
    const float* c2   = (const float*)d_in[2];
    const float* peW1 = (const float*)d_in[3];
    const float* peb1 = (const float*)d_in[4];
    const float* peW2 = (const float*)d_in[5];
    const float* peb2 = (const float*)d_in[6];
    const float* Wq   = (const float*)d_in[7];
    const float* Wk   = (const float*)d_in[8];
    const float* Wv   = (const float*)d_in[9];
    const float* lsc  = (const float*)d_in[10];
    const float* Wo   = (const float*)d_in[11];
    const float* bo   = (const float*)d_in[12];
    const float* g1   = (const float*)d_in[13];
    const float* be1  = (const float*)d_in[14];
    const float* g2   = (const float*)d_in[15];
    const float* be2  = (const float*)d_in[16];
    const float* g3   = (const float*)d_in[17];
    const float* be3  = (const float*)d_in[18];
    const float* mW1  = (const float*)d_in[19];
    const float* mb1  = (const float*)d_in[20];
    const float* mW2  = (const float*)d_in[21];
    const float* mb2  = (const float*)d_in[22];
    const float* muW1 = (const float*)d_in[23];
    const float* mub1 = (const float*)d_in[24];
    const float* muW2 = (const float*)d_in[25];
    const float* mub2 = (const float*)d_in[26];

    const size_t MB = (size_t)1 << 20;
    char* ws = (char*)d_ws;
    // Timeline-safe layout, 80.5 MiB total:
    //  [0,64M)   cand (u64, dead after merge1) -> hbuf[0,32M) -> y1h[0,16M)+y1l[16,32M)
    //  [32,64M)  hnh[32,48M) + hnl[48,64M)  (written by tok_mnh after cand dead)
    //  [64,72M)  c2c (dead after merge2)
    //  [72,80M)  w1th/w1tl/w2th/w2tl
    //  [80,80.5M) knn
    u64*            cand   = (u64*)(ws);
    float*          hbuf   = (float*)(ws);
    unsigned short* y1h    = (unsigned short*)(ws);
    unsigned short* y1l    = (unsigned short*)(ws + 16 * MB);
    unsigned short* hnh    = (unsigned short*)(ws + 32 * MB);
    unsigned short* hnl    = (unsigned short*)(ws + 48 * MB);
    u64*            c2c    = (u64*)(ws + 64 * MB);
    unsigned short* w1th   = (unsigned short*)(ws + 72 * MB);
    unsigned short* w1tl   = (unsigned short*)(ws + 74 * MB);
    unsigned short* w2th   = (unsigned short*)(ws + 76 * MB);
    unsigned short* w2tl   = (unsigned short*)(ws + 78 * MB);
    int*            knn    = (int*)(ws + 80 * MB);
    (void)in_sizes; (void)n_in; (void)out_size; (void)ws_size;

    wconv<<<dim3(16, 16, 2), 256, 0, stream>>>(muW1, muW2, w1th, w1tl, w2th, w2tl);
    topk_partial<<<dim3(TT / 256, NC, B_), 256, 0, stream>>>(c1, c2, cand);
    topk_merge1<<<dim3(TT / 64, 8, B_), 64, 0, stream>>>(cand, c2c);
    topk_merge2<<<dim3(TT / 64, B_), 64, 0, stream>>>(c2c, knn);
    tok_pe<<<dim3(512), 256, 0, stream>>>(x, c1, c2, knn, peW1, peb1, peW2, peb2, g1, be1, hbuf);
    tok_attn<<<dim3(512), 256, 0, stream>>>(x, knn, Wq, Wk, Wv, lsc, Wo, bo, g2, be2, hbuf);
    tok_mnh<<<dim3(512), 256, 0, stream>>>(hbuf, mW1, mb1, mW2, mb2, g3, be3, hnh, hnl);
    gemm_split<1><<<dim3(8, 64), 256, 0, stream>>>(hnh, hnl, w1th, w1tl, mub1,
                                                   y1h, y1l, (float*)nullptr, 8192, 1024, 1024);
    gemm_split<0><<<dim3(8, 64), 256, 0, stream>>>(y1h, y1l, w2th, w2tl, mub2,
                                                   (unsigned short*)nullptr, (unsigned short*)nullptr,
                                                   (float*)d_out, 8192, 1024, 1024);
}